// Round 1
// baseline (18564.035 us; speedup 1.0000x reference)
//
#include <hip/hip_runtime.h>

typedef unsigned short ushort;
typedef unsigned int uint;
typedef __attribute__((ext_vector_type(8))) short short8;
typedef __attribute__((ext_vector_type(4))) float f32x4;

#define DEVI __device__ __forceinline__

#define B_ 32
#define SIN_ 128
#define SOUT_ 32
#define Y_ 256
#define H_ 512
#define E_ 256
#define TH_ 1536

DEVI float b2f(ushort u){ return __uint_as_float(((uint)u)<<16); }
DEVI ushort f2b(float f){ uint x = __float_as_uint(f); return (ushort)((x + 0x7FFFu + ((x>>16)&1u)) >> 16); }
DEVI float sigf(float x){ return 1.f/(1.f+__expf(-x)); }
DEVI float tanh_fast(float x){ return 2.f/(1.f+__expf(-2.f*x)) - 1.f; }
DEVI float splus(float x){ return fmaxf(x,0.f) + log1pf(__expf(-fabsf(x))); }

// ---------------- init / reductions ----------------
__global__ void k_init(float* acc){ if (threadIdx.x < 4) acc[threadIdx.x] = 0.f; }

__global__ void k_wsfail(float* out){ out[0]=1.2345e8f; out[1]=2.3456e8f; out[2]=3.4567e8f; }

__global__ __launch_bounds__(256) void k_ysum(const float* __restrict__ yv, float* __restrict__ acc)
{
  __shared__ float red[256];
  float s = 0.f;
  for (long i = (long)blockIdx.x*256 + threadIdx.x; i < (long)B_*SOUT_*Y_; i += (long)gridDim.x*256) s += yv[i];
  red[threadIdx.x] = s; __syncthreads();
  for (int o=128;o;o>>=1){ if ((int)threadIdx.x<o) red[threadIdx.x] += red[threadIdx.x+o]; __syncthreads(); }
  if (threadIdx.x==0) atomicAdd(acc+2, red[0]);
}

// ---------------- embedding / lookup ----------------
__global__ void k_lookup(const int* __restrict__ x, const int* __restrict__ akey,
                         const int* __restrict__ atype, const int* __restrict__ croom,
                         const float* __restrict__ yv,
                         const float* __restrict__ emb, const float* __restrict__ attab,
                         ushort* __restrict__ embxs, ushort* __restrict__ aemb,
                         ushort* __restrict__ aembT, float* __restrict__ avec,
                         ushort* __restrict__ acat, ushort* __restrict__ yprev)
{
  const long N1 = (long)SIN_*B_*E_;
  const long N2 = (long)Y_*E_;
  const long N3 = (long)Y_*32;
  const long N4 = (long)SOUT_*B_*E_;
  const long N5 = (long)SOUT_*B_*Y_;
  for (long i = (long)blockIdx.x*blockDim.x + threadIdx.x; i < N1+N2+N3+N4+N5; i += (long)gridDim.x*blockDim.x){
    long id = i;
    if (id < N1){
      int e = id & 255; long sb = id >> 8; int bb = (int)(sb & 31); int s = (int)(sb >> 5);
      embxs[id] = f2b(emb[(size_t)x[bb*SIN_ + s]*E_ + e]);
    } else if ((id -= N1) < N2){
      int e = (int)(id & 255), yy = (int)(id >> 8);
      ushort v = f2b(emb[(size_t)akey[yy]*E_ + e]);
      aemb[yy*E_ + e] = v;
      aembT[e*Y_ + yy] = v;
    } else if ((id -= N2) < N3){
      int a = (int)(id & 31), yy = (int)(id >> 5);
      avec[yy*32 + a] = attab[atype[yy]*32 + a];
    } else if ((id -= N3) < N4){
      int e = (int)(id & 255); long tb = id >> 8; int bb = (int)(tb & 31); int t = (int)(tb >> 5);
      acat[(size_t)tb*512 + e] = f2b(emb[(size_t)croom[bb*SOUT_ + t]*E_ + e]);
    } else { id -= N4;
      int yy = (int)(id & 255); long tb = id >> 8; int bb = (int)(tb & 31); int t = (int)(tb >> 5);
      yprev[id] = (t == 0) ? (ushort)0 : f2b(yv[((size_t)bb*SOUT_ + (t-1))*Y_ + yy]);
    }
  }
}

// generic f32 -> bf16 strided convert
__global__ void k_conv(const float* __restrict__ src, ushort* __restrict__ dst,
                       int rows, int cols, int sld, int dld, int doff)
{
  for (long i = (long)blockIdx.x*blockDim.x + threadIdx.x; i < (long)rows*cols; i += (long)gridDim.x*blockDim.x){
    int c = (int)(i % cols); int r = (int)(i / cols);
    dst[(size_t)r*dld + doff + c] = f2b(src[(size_t)r*sld + c]);
  }
}

// add_y (atype @ W_atype^T + dec_bih), addc_y (atype @ W1_at^T + chk_b1), dense w_chk
__global__ void k_prep2(const float* __restrict__ avec, const float* __restrict__ decWih,
                        const float* __restrict__ dbih, const float* __restrict__ cW1,
                        const float* __restrict__ cb1,
                        float* __restrict__ addy, float* __restrict__ addcy, float* __restrict__ wchk)
{
  const long NA = (long)Y_*TH_;
  const long NB = (long)Y_*H_;
  for (long i = (long)blockIdx.x*blockDim.x + threadIdx.x; i < NA+NB+TH_; i += (long)gridDim.x*blockDim.x){
    long id = i;
    if (id < NA){
      int n = (int)(id % TH_), yy = (int)(id / TH_);
      float s = dbih[n];
      const float* wr = decWih + (size_t)n*1569 + 1281;
      const float* av = avec + yy*32;
      #pragma unroll
      for (int a=0;a<32;++a) s += av[a]*wr[a];
      addy[id] = s;
    } else if ((id -= NA) < NB){
      int n = (int)(id & 511), yy = (int)(id >> 9);
      float s = cb1[n];
      const float* wr = cW1 + (size_t)n*1568 + 1024;
      const float* av = avec + yy*32;
      #pragma unroll
      for (int a=0;a<32;++a) s += av[a]*wr[a];
      addcy[id] = s;
    } else { id -= NB;
      wchk[id] = decWih[(size_t)id*1569 + 1024];
    }
  }
}

// ---------------- bf16 NT GEMM: C[M,N] = A[M,K] @ W[N,K]^T  (MFMA 16x16x32) ----------------
#define GF_BIAS 1
#define GF_TANH 2
#define GF_WF32 4
#define GF_WBF16 8
#define GF_BIG 16
#define GF_ADDY 32

template<int FLAGS>
__global__ __launch_bounds__(256)
void gemm_nt(const ushort* __restrict__ A, const ushort* __restrict__ W,
             const float* __restrict__ bias,
             const float* __restrict__ addy, int lday,
             float* __restrict__ Cf, ushort* __restrict__ Cb, int ldC,
             int K, int ldA, int ldW, int n0,
             long zA, long zW, long zC,
             const ushort* __restrict__ chkbase, ushort* __restrict__ chkhid)
{
  const int z = blockIdx.z;
  A += (long)z*zA; W += (long)z*zW;
  const int bn = n0 + (blockIdx.x<<7);
  const int bm = (blockIdx.y<<7);
  const int tid = threadIdx.x;
  const int w = tid>>6, lane = tid&63;
  const int wm = (w>>1)<<6, wn = (w&1)<<6;
  const int rs = tid>>1;
  const int kh = (tid&1)<<5;
  __shared__ ushort lsA[8192];
  __shared__ ushort lsB[8192];
  f32x4 acc[4][4];
  #pragma unroll
  for (int i=0;i<4;++i)
    #pragma unroll
    for (int jj=0;jj<4;++jj) acc[i][jj] = 0.f;

  const ushort* pa = A + (size_t)(bm+rs)*ldA + kh;
  const ushort* pb = W + (size_t)(bn+rs)*ldW + kh;
  uint4 va[4], vb[4];
  #pragma unroll
  for (int i=0;i<4;++i){ va[i] = *(const uint4*)(pa + i*8); vb[i] = *(const uint4*)(pb + i*8); }
  const int nkt = K>>6;
  for (int kt=0; kt<nkt; ++kt){
    __syncthreads();
    #pragma unroll
    for (int i=0;i<4;++i){
      const int c = ((tid&1)<<2) + i;
      *(uint4*)&lsA[(size_t)((c<<7) + rs)<<3] = va[i];
      *(uint4*)&lsB[(size_t)((c<<7) + rs)<<3] = vb[i];
    }
    __syncthreads();
    if (kt+1 < nkt){
      const ushort* qa = pa + (size_t)(kt+1)*64;
      const ushort* qb = pb + (size_t)(kt+1)*64;
      #pragma unroll
      for (int i=0;i<4;++i){ va[i] = *(const uint4*)(qa + i*8); vb[i] = *(const uint4*)(qb + i*8); }
    }
    #pragma unroll
    for (int ks=0;ks<2;++ks){
      const int ch = (ks<<2) + (lane>>4);
      short8 af[4], bf[4];
      #pragma unroll
      for (int mi=0;mi<4;++mi) af[mi] = *(const short8*)&lsA[(size_t)((ch<<7) + wm + (mi<<4) + (lane&15))<<3];
      #pragma unroll
      for (int ni=0;ni<4;++ni) bf[ni] = *(const short8*)&lsB[(size_t)((ch<<7) + wn + (ni<<4) + (lane&15))<<3];
      #pragma unroll
      for (int mi=0;mi<4;++mi)
        #pragma unroll
        for (int ni=0;ni<4;++ni)
          acc[mi][ni] = __builtin_amdgcn_mfma_f32_16x16x32_bf16(af[mi], bf[ni], acc[mi][ni], 0,0,0);
    }
  }
  const long zc = (long)z*zC;
  #pragma unroll
  for (int mi=0;mi<4;++mi){
    #pragma unroll
    for (int ni=0;ni<4;++ni){
      const int col = bn + wn + (ni<<4) + (lane&15);
      const int row0 = bm + wm + (mi<<4) + ((lane>>4)<<2);
      float bv = 0.f;
      if (FLAGS & GF_BIAS){ if (!(FLAGS & GF_BIG) || col < TH_) bv = bias[col]; }
      #pragma unroll
      for (int q=0;q<4;++q){
        const int row = row0 + q;
        float xv = acc[mi][ni][q] + bv;
        if (FLAGS & GF_ADDY) xv += addy[(size_t)(row&255)*lday + col];
        if (FLAGS & GF_TANH) xv = tanh_fast(xv);
        if (FLAGS & GF_BIG){
          if (col < TH_) Cb[(size_t)row*TH_ + col] = f2b(xv);
          else {
            const int c2 = col - TH_;
            const float u = xv + b2f(chkbase[(size_t)row*H_ + c2]);
            chkhid[(size_t)row*H_ + c2] = f2b(tanh_fast(u));
          }
        } else {
          if (FLAGS & GF_WF32)  Cf[zc + (size_t)row*ldC + col] = xv;
          if (FLAGS & GF_WBF16) Cb[zc + (size_t)row*ldC + col] = f2b(xv);
        }
      }
    }
  }
}

// ---------------- encoder bi-GRU: one block per (dir, b) ----------------
__global__ __launch_bounds__(512)
void enc_rnn(const float* __restrict__ Wf, const float* __restrict__ Wb,
             const float* __restrict__ bhf, const float* __restrict__ bhb,
             const ushort* __restrict__ gif, const ushort* __restrict__ gib,
             ushort* __restrict__ encout, ushort* __restrict__ encoutT,
             float* __restrict__ hTf, float* __restrict__ hTb)
{
  const int bid = blockIdx.x;
  const int xcd = bid & 7, slot = bid >> 3;
  const int dir = (xcd >= 4) ? 1 : 0;
  const int b = ((xcd & 3) << 3) + slot;
  const float* W = dir ? Wb : Wf;
  const float* bh = dir ? bhb : bhf;
  const ushort* gi = dir ? gib : gif;
  const int j = threadIdx.x;
  __shared__ float h[H_];
  h[j] = 0.f;
  __syncthreads();
  const float* w0 = W + (size_t)j*H_;
  const float* w1 = W + (size_t)(H_+j)*H_;
  const float* w2 = W + (size_t)(2*H_+j)*H_;
  const float bh0 = bh[j], bh1 = bh[H_+j], bh2 = bh[2*H_+j];
  for (int it=0; it<SIN_; ++it){
    const int t = dir ? (SIN_-1-it) : it;
    float d0=0.f,d1=0.f,d2=0.f;
    #pragma unroll 8
    for (int k=0;k<H_;k+=4){
      const float4 hv = *(const float4*)&h[k];
      const float4 a0 = *(const float4*)&w0[k];
      const float4 a1 = *(const float4*)&w1[k];
      const float4 a2 = *(const float4*)&w2[k];
      d0 += hv.x*a0.x + hv.y*a0.y + hv.z*a0.z + hv.w*a0.w;
      d1 += hv.x*a1.x + hv.y*a1.y + hv.z*a1.z + hv.w*a1.w;
      d2 += hv.x*a2.x + hv.y*a2.y + hv.z*a2.z + hv.w*a2.w;
    }
    const ushort* gr = gi + ((size_t)t*B_ + b)*TH_;
    const float gi0 = b2f(gr[j]), gi1 = b2f(gr[H_+j]), gi2 = b2f(gr[2*H_+j]);
    const float hold = h[j];
    const float r  = sigf(gi0 + d0 + bh0);
    const float zg = sigf(gi1 + d1 + bh1);
    const float n  = tanh_fast(gi2 + r*(d2 + bh2));
    const float h2 = (1.f - zg)*n + zg*hold;
    __syncthreads();
    h[j] = h2;
    const ushort hbv = f2b(h2);
    encout[((size_t)b*SIN_ + t)*1024 + dir*H_ + j] = hbv;
    encoutT[((size_t)b*1024 + dir*H_ + j)*SIN_ + t] = hbv;
    __syncthreads();
  }
  (dir ? hTb : hTf)[(size_t)b*H_ + j] = h[j];
}

// embsum = bf16(emb + trans)
__global__ void k_embsum(const ushort* __restrict__ embxs, const float* __restrict__ transo,
                         ushort* __restrict__ esum)
{
  for (long i = (long)blockIdx.x*blockDim.x + threadIdx.x; i < (long)B_*SIN_*E_; i += (long)gridDim.x*blockDim.x){
    int e = (int)(i & 255); long bs = i >> 8; int s = (int)(bs & 127); int bb = (int)(bs >> 7);
    esum[i] = f2b(b2f(embxs[((size_t)s*B_ + bb)*E_ + e]) + transo[i]);
  }
}

// row softmax over SIN=128, one wave per row
__global__ __launch_bounds__(256) void k_softmax(const float* __restrict__ sc, ushort* __restrict__ al)
{
  const int row = blockIdx.x*4 + (threadIdx.x>>6);
  const int lane = threadIdx.x&63;
  const float* s = sc + (size_t)row*SIN_;
  const float2 v = *(const float2*)&s[lane*2];
  float m = fmaxf(v.x, v.y);
  #pragma unroll
  for (int o=1;o<64;o<<=1) m = fmaxf(m, __shfl_xor(m, o));
  const float e0 = __expf(v.x - m), e1 = __expf(v.y - m);
  float sum = e0 + e1;
  #pragma unroll
  for (int o=1;o<64;o<<=1) sum += __shfl_xor(sum, o);
  const float inv = 1.f/sum;
  ushort* a = al + (size_t)row*SIN_;
  const uint pkv = (uint)f2b(e0*inv) | ((uint)f2b(e1*inv)<<16);
  *(uint*)&a[lane*2] = pkv;
}

// h0_dec = tanh(hidden_cat @ merge_W^T + merge_b), with the reference's odd reshape
__global__ __launch_bounds__(512)
void k_merge(const float* __restrict__ hTf, const float* __restrict__ hTb,
             const float* __restrict__ mW, const float* __restrict__ mb,
             float* __restrict__ h0)
{
  const int b = blockIdx.x, j = threadIdx.x;
  __shared__ float hc[1024];
  for (int i=j; i<1024; i+=512){
    const int half = i >> 9, jj = i & 511;
    hc[i] = (b < 16) ? hTf[(size_t)(2*b + half)*H_ + jj] : hTb[(size_t)(2*(b-16) + half)*H_ + jj];
  }
  __syncthreads();
  float d = mb[j];
  const float* wr = mW + (size_t)j*1024;
  #pragma unroll 8
  for (int k=0;k<1024;k+=4){
    const float4 a = *(const float4*)&wr[k];
    const float4 hh = *(const float4*)&hc[k];
    d += a.x*hh.x + a.y*hh.y + a.z*hh.z + a.w*hh.w;
  }
  h0[(size_t)b*H_ + j] = tanh_fast(d);
}

__global__ void k_bcast(const float* __restrict__ h0, float* __restrict__ hf, ushort* __restrict__ hb)
{
  for (long i = (long)blockIdx.x*blockDim.x + threadIdx.x; i < (long)8192*H_; i += (long)gridDim.x*blockDim.x){
    const int jj = (int)(i & 511); const long row = i >> 9; const int bb = (int)(row >> 8);
    const float v = h0[(size_t)bb*H_ + jj];
    hf[i] = v; hb[i] = f2b(v);
  }
}

// ---------------- decoder gates + logits ----------------
__global__ __launch_bounds__(256)
void dec_gates(const ushort* __restrict__ gh, const ushort* __restrict__ gib,
               const float* __restrict__ hin, const float* __restrict__ sp_t,
               const float* __restrict__ wchk, const float* __restrict__ checked,
               const float* __restrict__ decW, int t,
               float* __restrict__ hout, ushort* __restrict__ h2b,
               float* __restrict__ logits)
{
  const int tid = threadIdx.x;
  const int row = blockIdx.x*32 + (tid>>3);
  const int bb = row>>8, yy = row&255;
  const int j0 = (tid&7)<<6;
  const float ck = checked[((size_t)bb*33 + t)*Y_ + yy];
  const ushort* ghr = gh + (size_t)row*TH_;
  const ushort* gir = gib + (size_t)row*TH_;
  const float* hr = hin + (size_t)row*H_;
  const float* sp = sp_t + (size_t)bb*TH_;
  float* ho = hout + (size_t)row*H_;
  ushort* hbw = h2b + (size_t)row*H_;
  float lacc = 0.f;
  for (int c8=0;c8<8;++c8){
    const int j = j0 + (c8<<3);
    const uint4 g0 = *(const uint4*)&ghr[j];
    const uint4 g1 = *(const uint4*)&ghr[H_+j];
    const uint4 g2 = *(const uint4*)&ghr[2*H_+j];
    const uint4 i0 = *(const uint4*)&gir[j];
    const uint4 i1 = *(const uint4*)&gir[H_+j];
    const uint4 i2 = *(const uint4*)&gir[2*H_+j];
    const float4 hv0 = *(const float4*)&hr[j];
    const float4 hv1 = *(const float4*)&hr[j+4];
    const float4 sr0 = *(const float4*)&sp[j],        sr1 = *(const float4*)&sp[j+4];
    const float4 sz0 = *(const float4*)&sp[H_+j],     sz1 = *(const float4*)&sp[H_+j+4];
    const float4 sn0 = *(const float4*)&sp[2*H_+j],   sn1 = *(const float4*)&sp[2*H_+j+4];
    const float4 wr0 = *(const float4*)&wchk[j],      wr1 = *(const float4*)&wchk[j+4];
    const float4 wz0 = *(const float4*)&wchk[H_+j],   wz1 = *(const float4*)&wchk[H_+j+4];
    const float4 wn0 = *(const float4*)&wchk[2*H_+j], wn1 = *(const float4*)&wchk[2*H_+j+4];
    const float4 dw0 = *(const float4*)&decW[j],      dw1 = *(const float4*)&decW[j+4];
    const float hva[8] = {hv0.x,hv0.y,hv0.z,hv0.w,hv1.x,hv1.y,hv1.z,hv1.w};
    const float sra[8] = {sr0.x,sr0.y,sr0.z,sr0.w,sr1.x,sr1.y,sr1.z,sr1.w};
    const float sza[8] = {sz0.x,sz0.y,sz0.z,sz0.w,sz1.x,sz1.y,sz1.z,sz1.w};
    const float sna[8] = {sn0.x,sn0.y,sn0.z,sn0.w,sn1.x,sn1.y,sn1.z,sn1.w};
    const float wra[8] = {wr0.x,wr0.y,wr0.z,wr0.w,wr1.x,wr1.y,wr1.z,wr1.w};
    const float wza[8] = {wz0.x,wz0.y,wz0.z,wz0.w,wz1.x,wz1.y,wz1.z,wz1.w};
    const float wna[8] = {wn0.x,wn0.y,wn0.z,wn0.w,wn1.x,wn1.y,wn1.z,wn1.w};
    const float dwa[8] = {dw0.x,dw0.y,dw0.z,dw0.w,dw1.x,dw1.y,dw1.z,dw1.w};
    const ushort* p0 = (const ushort*)&g0;
    const ushort* p1 = (const ushort*)&g1;
    const ushort* p2 = (const ushort*)&g2;
    const ushort* p3 = (const ushort*)&i0;
    const ushort* p4 = (const ushort*)&i1;
    const ushort* p5 = (const ushort*)&i2;
    float h2a[8];
    uint pk[4] = {0u,0u,0u,0u};
    #pragma unroll
    for (int e=0;e<8;++e){
      const float gn_ = b2f(p2[e]);
      const float xr = b2f(p3[e]) + sra[e] + ck*wra[e] + b2f(p0[e]);
      const float xz = b2f(p4[e]) + sza[e] + ck*wza[e] + b2f(p1[e]);
      const float xn = b2f(p5[e]) + sna[e] + ck*wna[e];
      const float r  = sigf(xr);
      const float zg = sigf(xz);
      const float n  = tanh_fast(xn + r*gn_);
      const float h2 = (1.f - zg)*n + zg*hva[e];
      h2a[e] = h2;
      pk[e>>1] |= ((uint)f2b(h2)) << ((e&1)<<4);
      lacc += h2 * dwa[e];
    }
    *(float4*)&ho[j]   = make_float4(h2a[0],h2a[1],h2a[2],h2a[3]);
    *(float4*)&ho[j+4] = make_float4(h2a[4],h2a[5],h2a[6],h2a[7]);
    *(uint4*)&hbw[j]   = make_uint4(pk[0],pk[1],pk[2],pk[3]);
  }
  lacc += __shfl_xor(lacc, 1);
  lacc += __shfl_xor(lacc, 2);
  lacc += __shfl_xor(lacc, 4);
  if ((tid&7)==0) logits[row] = lacc;
}

// ---------------- per-step losses ----------------
__global__ __launch_bounds__(256)
void dec_loss(const ushort* __restrict__ chkhid, const float* __restrict__ cw2,
              const float* __restrict__ cb2v, const float* __restrict__ checked,
              const float* __restrict__ yv, const float* __restrict__ logits,
              int t, float* __restrict__ acc)
{
  const int tid = threadIdx.x;
  if (blockIdx.x < 64){
    const int wv = tid>>6, lane = tid&63;
    const float4 w20 = *(const float4*)&cw2[lane*8];
    const float4 w21 = *(const float4*)&cw2[lane*8+4];
    const float w2a[8] = {w20.x,w20.y,w20.z,w20.w,w21.x,w21.y,w21.z,w21.w};
    const float bb2 = cb2v[0];
    float wsum = 0.f;
    for (int i=0;i<32;++i){
      const int row = blockIdx.x*128 + wv*32 + i;
      const uint4 hv = *(const uint4*)&chkhid[(size_t)row*H_ + lane*8];
      const ushort* ph = (const ushort*)&hv;
      float p = 0.f;
      #pragma unroll
      for (int e=0;e<8;++e) p += b2f(ph[e]) * w2a[e];
      #pragma unroll
      for (int o=1;o<64;o<<=1) p += __shfl_xor(p, o);
      if (lane==0){
        const int bb = row>>8, yy = row&255;
        const float u = p + bb2;
        const float c = checked[((size_t)bb*33 + (t+1))*Y_ + yy];
        const float yt = yv[((size_t)bb*SOUT_ + t)*Y_ + yy];
        wsum += yt * (c*splus(-u) + (1.f-c)*splus(u));
      }
    }
    if (lane==0) atomicAdd(acc+1, wsum);
  } else {
    __shared__ float red[256];
    __shared__ float bmx[32], bsm[32];
    const int bb = tid>>3, part = tid&7;
    float lv[32];
    const float* lg = logits + bb*Y_ + part*32;
    float m = -1e30f;
    #pragma unroll
    for (int i=0;i<32;++i){ lv[i] = lg[i]; m = fmaxf(m, lv[i]); }
    red[tid] = m; __syncthreads();
    if (part==0){ float mm = red[tid];
      #pragma unroll
      for (int k2=1;k2<8;++k2) mm = fmaxf(mm, red[tid+k2]);
      bmx[bb] = mm; }
    __syncthreads();
    const float bm = bmx[bb];
    float se = 0.f;
    #pragma unroll
    for (int i=0;i<32;++i) se += __expf(lv[i]-bm);
    red[tid] = se; __syncthreads();
    if (part==0){ float ss = 0.f;
      #pragma unroll
      for (int k2=0;k2<8;++k2) ss += red[tid+k2];
      bsm[bb] = ss; }
    __syncthreads();
    const float lse = bm + logf(bsm[bb]);
    const float* yr = yv + ((size_t)bb*SOUT_ + t)*Y_ + part*32;
    float pl = 0.f;
    #pragma unroll
    for (int i=0;i<32;++i) pl += yr[i]*(lv[i]-lse);
    red[tid] = pl; __syncthreads();
    if (tid==0){ float s = 0.f;
      for (int k2=0;k2<256;++k2) s += red[k2];
      atomicAdd(acc+0, -s); }
  }
}

__global__ void k_final(const float* __restrict__ acc, float* __restrict__ out)
{
  if (threadIdx.x==0){
    const float ls = acc[0], cls = acc[1], ys = acc[2];
    out[0] = (ls+cls)/ys; out[1] = ls/ys; out[2] = cls/ys;
  }
}

// ---------------- host ----------------
extern "C" void kernel_launch(void* const* d_in, const int* in_sizes, int n_in,
                              void* d_out, int out_size, void* d_ws, size_t ws_size,
                              hipStream_t stream)
{
  (void)in_sizes; (void)n_in; (void)out_size;
  const int*   x      = (const int*)d_in[0];
  const int*   akey   = (const int*)d_in[1];
  const int*   atype  = (const int*)d_in[2];
  const int*   croom  = (const int*)d_in[3];
  const float* checked= (const float*)d_in[4];
  const float* yv     = (const float*)d_in[5];
  const float* emb    = (const float*)d_in[6];
  const float* attab  = (const float*)d_in[7];
  const float* eWihF  = (const float*)d_in[8];
  const float* eWhhF  = (const float*)d_in[9];
  const float* ebihF  = (const float*)d_in[10];
  const float* ebhhF  = (const float*)d_in[11];
  const float* eWihB  = (const float*)d_in[12];
  const float* eWhhB  = (const float*)d_in[13];
  const float* ebihB  = (const float*)d_in[14];
  const float* ebhhB  = (const float*)d_in[15];
  const float* transW = (const float*)d_in[16];
  const float* transb = (const float*)d_in[17];
  const float* mergeW = (const float*)d_in[18];
  const float* mergeb = (const float*)d_in[19];
  const float* dWih   = (const float*)d_in[20];
  const float* dWhh   = (const float*)d_in[21];
  const float* dbih   = (const float*)d_in[22];
  const float* dbhh   = (const float*)d_in[23];
  const float* dW     = (const float*)d_in[24];
  const float* cW1    = (const float*)d_in[26];
  const float* cb1    = (const float*)d_in[27];
  const float* cW2    = (const float*)d_in[28];
  const float* cb2    = (const float*)d_in[29];

  char* base = (char*)d_ws;
  size_t off = 0;
  auto alloc = [&](size_t bytes)->char*{ char* p = base + off; off += (bytes + 255) & ~(size_t)255; return p; };

  float*  accv   = (float*)alloc(256);
  ushort* embxs  = (ushort*)alloc((size_t)SIN_*B_*E_*2);
  ushort* aemb   = (ushort*)alloc((size_t)Y_*E_*2);
  ushort* aembT  = (ushort*)alloc((size_t)Y_*E_*2);
  float*  avec   = (float*)alloc((size_t)Y_*32*4);
  ushort* yprev  = (ushort*)alloc((size_t)SOUT_*B_*Y_*2);
  ushort* acat   = (ushort*)alloc((size_t)SOUT_*B_*512*2);
  ushort* gi_fb  = (ushort*)alloc((size_t)2*SIN_*B_*TH_*2);   // gi_f | gi_b ; later aliased by gi_base (exact size)
  ushort* gi_f   = gi_fb;
  ushort* gi_b   = gi_fb + (size_t)SIN_*B_*TH_;
  ushort* gibase = gi_fb;
  ushort* encout = (ushort*)alloc((size_t)B_*SIN_*1024*2);    // + encoutT region reused as hbuf0
  ushort* encoutT= (ushort*)alloc((size_t)B_*1024*SIN_*2);
  float*  hbuf0  = (float*)encout;                            // 8192*512*4 == encout+encoutT exactly
  float*  hTf    = (float*)alloc((size_t)B_*H_*4);
  float*  hTb    = (float*)alloc((size_t)B_*H_*4);
  float*  h0dec  = (float*)alloc((size_t)B_*H_*4);
  float*  transo = (float*)alloc((size_t)B_*SIN_*E_*4);       // start of region reused as gh
  ushort* esum   = (ushort*)alloc((size_t)B_*SIN_*E_*2);
  float*  scores = (float*)alloc((size_t)B_*Y_*SIN_*4);
  ushort* alpha  = (ushort*)alloc((size_t)B_*Y_*SIN_*2);
  ushort* att    = (ushort*)alloc((size_t)8192*1024*2);
  ushort* gh     = (ushort*)transo;                           // 25.2MB <= transo..att region (29.3MB)
  ushort* chkbase= (ushort*)alloc((size_t)8192*H_*2);
  float*  addy   = (float*)alloc((size_t)Y_*TH_*4);
  float*  addcy  = (float*)alloc((size_t)Y_*H_*4);
  float*  sproj  = (float*)alloc((size_t)SOUT_*B_*TH_*4);
  float*  wchk   = (float*)alloc((size_t)TH_*4);
  ushort* WihFb  = (ushort*)alloc((size_t)TH_*E_*2);
  ushort* WihBb  = (ushort*)alloc((size_t)TH_*E_*2);
  ushort* Wtrb   = (ushort*)alloc((size_t)E_*1024*2);
  ushort* Wattb  = (ushort*)alloc((size_t)TH_*1024*2);
  ushort* Wcat2b = (ushort*)alloc((size_t)TH_*512*2);
  ushort* W1attb = (ushort*)alloc((size_t)H_*1024*2);
  ushort* Wbigb  = (ushort*)alloc((size_t)2048*512*2);
  float*  hbuf1  = (float*)alloc((size_t)8192*H_*4);
  ushort* h2b    = (ushort*)alloc((size_t)8192*H_*2);
  ushort* chkhid = (ushort*)alloc((size_t)8192*H_*2);
  float*  logits = (float*)alloc((size_t)8192*4);

  if (off > ws_size){ k_wsfail<<<1,1,0,stream>>>((float*)d_out); return; }

  float* outp = (float*)d_out;

  k_init<<<dim3(1), dim3(64), 0, stream>>>(accv);
  k_ysum<<<dim3(256), dim3(256), 0, stream>>>(yv, accv);
  k_lookup<<<dim3(2048), dim3(256), 0, stream>>>(x, akey, atype, croom, yv, emb, attab,
                                                 embxs, aemb, aembT, avec, acat, yprev);
  auto conv = [&](const float* s, ushort* d, int r, int c, int sld, int dld, int doff){
    k_conv<<<dim3(512), dim3(256), 0, stream>>>(s, d, r, c, sld, dld, doff);
  };
  conv(eWihF, WihFb, TH_, E_, E_, E_, 0);
  conv(eWihB, WihBb, TH_, E_, E_, E_, 0);
  conv(transW, Wtrb, E_, 1024, 1024, 1024, 0);
  conv(dWih, Wattb, TH_, 1024, 1569, 1024, 0);
  conv(dWih+1025, Wcat2b, TH_, 256, 1569, 512, 0);
  conv(dWih+1313, Wcat2b, TH_, 256, 1569, 512, 256);
  conv(cW1, W1attb, H_, 1024, 1568, 1024, 0);
  conv(dWhh, Wbigb, TH_, 512, 512, 512, 0);
  conv(cW1+1056, Wbigb + (size_t)TH_*512, H_, 512, 1568, 512, 0);
  k_prep2<<<dim3(1024), dim3(256), 0, stream>>>(avec, dWih, dbih, cW1, cb1, addy, addcy, wchk);

  // encoder input projections (bias folded in)
  gemm_nt<(GF_BIAS|GF_WBF16)><<<dim3(12,32,1), dim3(256), 0, stream>>>(
    embxs, WihFb, ebihF, nullptr, 0, nullptr, gi_f, TH_, E_, E_, E_, 0, 0L,0L,0L, nullptr, nullptr);
  gemm_nt<(GF_BIAS|GF_WBF16)><<<dim3(12,32,1), dim3(256), 0, stream>>>(
    embxs, WihBb, ebihB, nullptr, 0, nullptr, gi_b, TH_, E_, E_, E_, 0, 0L,0L,0L, nullptr, nullptr);

  enc_rnn<<<dim3(64), dim3(512), 0, stream>>>(eWhhF, eWhhB, ebhhF, ebhhB, gi_f, gi_b,
                                              encout, encoutT, hTf, hTb);

  // trans_out = tanh(enc_out @ trans_W^T + b)
  gemm_nt<(GF_BIAS|GF_TANH|GF_WF32)><<<dim3(2,32,1), dim3(256), 0, stream>>>(
    encout, Wtrb, transb, nullptr, 0, transo, nullptr, E_, 1024, 1024, 1024, 0, 0L,0L,0L, nullptr, nullptr);
  k_embsum<<<dim3(1024), dim3(256), 0, stream>>>(embxs, transo, esum);

  // scores[b] = action_emb @ embsum_b^T  (batched over b)
  gemm_nt<GF_WF32><<<dim3(1,2,32), dim3(256), 0, stream>>>(
    aemb, esum, nullptr, nullptr, 0, scores, nullptr, SIN_, E_, E_, E_, 0,
    0L, (long)SIN_*E_, (long)Y_*SIN_, nullptr, nullptr);
  k_softmax<<<dim3(2048), dim3(256), 0, stream>>>(scores, alpha);

  // attention[b] = alpha_b @ enc_out_b   (W = enc_outT_b)
  gemm_nt<GF_WBF16><<<dim3(8,2,32), dim3(256), 0, stream>>>(
    alpha, encoutT, nullptr, nullptr, 0, nullptr, att, 1024, SIN_, SIN_, SIN_, 0,
    (long)Y_*SIN_, (long)1024*SIN_, (long)Y_*1024, nullptr, nullptr);

  k_merge<<<dim3(32), dim3(512), 0, stream>>>(hTf, hTb, mergeW, mergeb, h0dec);

  // yemb -> acat[:,256:512]
  gemm_nt<GF_WBF16><<<dim3(2,8,1), dim3(256), 0, stream>>>(
    yprev, aembT, nullptr, nullptr, 0, nullptr, acat+256, 512, Y_, Y_, Y_, 0, 0L,0L,0L, nullptr, nullptr);
  // sproj = acat @ Wcat2^T  (room + y parts of dec_Wih, all 32 steps)
  gemm_nt<GF_WF32><<<dim3(12,8,1), dim3(256), 0, stream>>>(
    acat, Wcat2b, nullptr, nullptr, 0, sproj, nullptr, TH_, 512, 512, 512, 0, 0L,0L,0L, nullptr, nullptr);

  // gi_base = att @ W_att^T + add_y[y]   ;  chk_base = att @ W1_att^T + addc_y[y]
  gemm_nt<(GF_WBF16|GF_ADDY)><<<dim3(12,64,1), dim3(256), 0, stream>>>(
    att, Wattb, nullptr, addy, TH_, nullptr, gibase, TH_, 1024, 1024, 1024, 0, 0L,0L,0L, nullptr, nullptr);
  gemm_nt<(GF_WBF16|GF_ADDY)><<<dim3(4,64,1), dim3(256), 0, stream>>>(
    att, W1attb, nullptr, addcy, H_, nullptr, chkbase, H_, 1024, 1024, 1024, 0, 0L,0L,0L, nullptr, nullptr);

  k_bcast<<<dim3(4096), dim3(256), 0, stream>>>(h0dec, hbuf0, h2b);

  // prologue: gh for t=0
  gemm_nt<(GF_BIG|GF_BIAS)><<<dim3(12,64,1), dim3(256), 0, stream>>>(
    h2b, Wbigb, dbhh, nullptr, 0, nullptr, gh, TH_, H_, H_, H_, 0, 0L,0L,0L, chkbase, chkhid);

  for (int t=0; t<SOUT_; ++t){
    float* hin  = (t&1) ? hbuf1 : hbuf0;
    float* hout = (t&1) ? hbuf0 : hbuf1;
    dec_gates<<<dim3(256), dim3(256), 0, stream>>>(gh, gibase, hin, sproj + (size_t)t*B_*TH_,
                                                   wchk, checked, dW, t, hout, h2b, logits);
    if (t < SOUT_-1){
      gemm_nt<(GF_BIG|GF_BIAS)><<<dim3(16,64,1), dim3(256), 0, stream>>>(
        h2b, Wbigb, dbhh, nullptr, 0, nullptr, gh, TH_, H_, H_, H_, 0, 0L,0L,0L, chkbase, chkhid);
    } else {
      gemm_nt<(GF_BIG|GF_BIAS)><<<dim3(4,64,1), dim3(256), 0, stream>>>(
        h2b, Wbigb, dbhh, nullptr, 0, nullptr, gh, TH_, H_, H_, H_, TH_, 0L,0L,0L, chkbase, chkhid);
    }
    dec_loss<<<dim3(65), dim3(256), 0, stream>>>(chkhid, cW2, cb2, checked, yv, logits, t, accv);
  }
  k_final<<<dim3(1), dim3(1), 0, stream>>>(accv, outp);
}

// Round 2
// 9133.836 us; speedup vs baseline: 2.0324x; 2.0324x over previous
//
#include <hip/hip_runtime.h>

typedef unsigned short ushort;
typedef unsigned int uint;
typedef __attribute__((ext_vector_type(8))) short short8;
typedef __attribute__((ext_vector_type(4))) float f32x4;

#define DEVI __device__ __forceinline__

#define B_ 32
#define SIN_ 128
#define SOUT_ 32
#define Y_ 256
#define H_ 512
#define E_ 256
#define TH_ 1536

DEVI float b2f(ushort u){ return __uint_as_float(((uint)u)<<16); }
DEVI ushort f2b(float f){ uint x = __float_as_uint(f); return (ushort)((x + 0x7FFFu + ((x>>16)&1u)) >> 16); }
DEVI float sigf(float x){ return 1.f/(1.f+__expf(-x)); }
DEVI float tanh_fast(float x){ return 2.f/(1.f+__expf(-2.f*x)) - 1.f; }
DEVI float splus(float x){ return fmaxf(x,0.f) + log1pf(__expf(-fabsf(x))); }

// ---------------- init / reductions ----------------
__global__ void k_init(float* acc){ if (threadIdx.x < 4) acc[threadIdx.x] = 0.f; }

__global__ void k_wsfail(float* out){ out[0]=1.2345e8f; out[1]=2.3456e8f; out[2]=3.4567e8f; }

// zero barrier counters + h exchange buffers
__global__ void k_init_enc(uint* __restrict__ cnt, ushort* __restrict__ hG)
{
  const int id = blockIdx.x*256 + threadIdx.x;
  if (id < 256) cnt[id] = 0u;
  // hG: 2 buf * 2 dir * 32 * 1024 ushorts = 131072 ushorts = 16384 uint4
  if (id < 16384) ((uint4*)hG)[id] = make_uint4(0,0,0,0);
}

__global__ __launch_bounds__(256) void k_ysum(const float* __restrict__ yv, float* __restrict__ acc)
{
  __shared__ float red[256];
  float s = 0.f;
  for (long i = (long)blockIdx.x*256 + threadIdx.x; i < (long)B_*SOUT_*Y_; i += (long)gridDim.x*256) s += yv[i];
  red[threadIdx.x] = s; __syncthreads();
  for (int o=128;o;o>>=1){ if ((int)threadIdx.x<o) red[threadIdx.x] += red[threadIdx.x+o]; __syncthreads(); }
  if (threadIdx.x==0) atomicAdd(acc+2, red[0]);
}

// ---------------- embedding / lookup ----------------
__global__ void k_lookup(const int* __restrict__ x, const int* __restrict__ akey,
                         const int* __restrict__ atype, const int* __restrict__ croom,
                         const float* __restrict__ yv,
                         const float* __restrict__ emb, const float* __restrict__ attab,
                         ushort* __restrict__ embxs, ushort* __restrict__ aemb,
                         ushort* __restrict__ aembT, float* __restrict__ avec,
                         ushort* __restrict__ acat, ushort* __restrict__ yprev)
{
  const long N1 = (long)SIN_*B_*E_;
  const long N2 = (long)Y_*E_;
  const long N3 = (long)Y_*32;
  const long N4 = (long)SOUT_*B_*E_;
  const long N5 = (long)SOUT_*B_*Y_;
  for (long i = (long)blockIdx.x*blockDim.x + threadIdx.x; i < N1+N2+N3+N4+N5; i += (long)gridDim.x*blockDim.x){
    long id = i;
    if (id < N1){
      int e = id & 255; long sb = id >> 8; int bb = (int)(sb & 31); int s = (int)(sb >> 5);
      embxs[id] = f2b(emb[(size_t)x[bb*SIN_ + s]*E_ + e]);
    } else if ((id -= N1) < N2){
      int e = (int)(id & 255), yy = (int)(id >> 8);
      ushort v = f2b(emb[(size_t)akey[yy]*E_ + e]);
      aemb[yy*E_ + e] = v;
      aembT[e*Y_ + yy] = v;
    } else if ((id -= N2) < N3){
      int a = (int)(id & 31), yy = (int)(id >> 5);
      avec[yy*32 + a] = attab[atype[yy]*32 + a];
    } else if ((id -= N3) < N4){
      int e = (int)(id & 255); long tb = id >> 8; int bb = (int)(tb & 31); int t = (int)(tb >> 5);
      acat[(size_t)tb*512 + e] = f2b(emb[(size_t)croom[bb*SOUT_ + t]*E_ + e]);
    } else { id -= N4;
      int yy = (int)(id & 255); long tb = id >> 8; int bb = (int)(tb & 31); int t = (int)(tb >> 5);
      yprev[id] = (t == 0) ? (ushort)0 : f2b(yv[((size_t)bb*SOUT_ + (t-1))*Y_ + yy]);
    }
  }
}

// generic f32 -> bf16 strided convert
__global__ void k_conv(const float* __restrict__ src, ushort* __restrict__ dst,
                       int rows, int cols, int sld, int dld, int doff)
{
  for (long i = (long)blockIdx.x*blockDim.x + threadIdx.x; i < (long)rows*cols; i += (long)gridDim.x*blockDim.x){
    int c = (int)(i % cols); int r = (int)(i / cols);
    dst[(size_t)r*dld + doff + c] = f2b(src[(size_t)r*sld + c]);
  }
}

// add_y (atype @ W_atype^T + dec_bih), addc_y (atype @ W1_at^T + chk_b1), dense w_chk
__global__ void k_prep2(const float* __restrict__ avec, const float* __restrict__ decWih,
                        const float* __restrict__ dbih, const float* __restrict__ cW1,
                        const float* __restrict__ cb1,
                        float* __restrict__ addy, float* __restrict__ addcy, float* __restrict__ wchk)
{
  const long NA = (long)Y_*TH_;
  const long NB = (long)Y_*H_;
  for (long i = (long)blockIdx.x*blockDim.x + threadIdx.x; i < NA+NB+TH_; i += (long)gridDim.x*blockDim.x){
    long id = i;
    if (id < NA){
      int n = (int)(id % TH_), yy = (int)(id / TH_);
      float s = dbih[n];
      const float* wr = decWih + (size_t)n*1569 + 1281;
      const float* av = avec + yy*32;
      #pragma unroll
      for (int a=0;a<32;++a) s += av[a]*wr[a];
      addy[id] = s;
    } else if ((id -= NA) < NB){
      int n = (int)(id & 511), yy = (int)(id >> 9);
      float s = cb1[n];
      const float* wr = cW1 + (size_t)n*1568 + 1024;
      const float* av = avec + yy*32;
      #pragma unroll
      for (int a=0;a<32;++a) s += av[a]*wr[a];
      addcy[id] = s;
    } else { id -= NB;
      wchk[id] = decWih[(size_t)id*1569 + 1024];
    }
  }
}

// ---------------- bf16 NT GEMM: C[M,N] = A[M,K] @ W[N,K]^T  (MFMA 16x16x32) ----------------
#define GF_BIAS 1
#define GF_TANH 2
#define GF_WF32 4
#define GF_WBF16 8
#define GF_BIG 16
#define GF_ADDY 32

template<int FLAGS>
__global__ __launch_bounds__(256)
void gemm_nt(const ushort* __restrict__ A, const ushort* __restrict__ W,
             const float* __restrict__ bias,
             const float* __restrict__ addy, int lday,
             float* __restrict__ Cf, ushort* __restrict__ Cb, int ldC,
             int K, int ldA, int ldW, int n0,
             long zA, long zW, long zC,
             const ushort* __restrict__ chkbase, ushort* __restrict__ chkhid)
{
  const int z = blockIdx.z;
  A += (long)z*zA; W += (long)z*zW;
  const int bn = n0 + (blockIdx.x<<7);
  const int bm = (blockIdx.y<<7);
  const int tid = threadIdx.x;
  const int w = tid>>6, lane = tid&63;
  const int wm = (w>>1)<<6, wn = (w&1)<<6;
  const int rs = tid>>1;
  const int kh = (tid&1)<<5;
  __shared__ ushort lsA[8192];
  __shared__ ushort lsB[8192];
  f32x4 acc[4][4];
  #pragma unroll
  for (int i=0;i<4;++i)
    #pragma unroll
    for (int jj=0;jj<4;++jj) acc[i][jj] = 0.f;

  const ushort* pa = A + (size_t)(bm+rs)*ldA + kh;
  const ushort* pb = W + (size_t)(bn+rs)*ldW + kh;
  uint4 va[4], vb[4];
  #pragma unroll
  for (int i=0;i<4;++i){ va[i] = *(const uint4*)(pa + i*8); vb[i] = *(const uint4*)(pb + i*8); }
  const int nkt = K>>6;
  for (int kt=0; kt<nkt; ++kt){
    __syncthreads();
    #pragma unroll
    for (int i=0;i<4;++i){
      const int c = ((tid&1)<<2) + i;
      *(uint4*)&lsA[(size_t)((c<<7) + rs)<<3] = va[i];
      *(uint4*)&lsB[(size_t)((c<<7) + rs)<<3] = vb[i];
    }
    __syncthreads();
    if (kt+1 < nkt){
      const ushort* qa = pa + (size_t)(kt+1)*64;
      const ushort* qb = pb + (size_t)(kt+1)*64;
      #pragma unroll
      for (int i=0;i<4;++i){ va[i] = *(const uint4*)(qa + i*8); vb[i] = *(const uint4*)(qb + i*8); }
    }
    #pragma unroll
    for (int ks=0;ks<2;++ks){
      const int ch = (ks<<2) + (lane>>4);
      short8 af[4], bf[4];
      #pragma unroll
      for (int mi=0;mi<4;++mi) af[mi] = *(const short8*)&lsA[(size_t)((ch<<7) + wm + (mi<<4) + (lane&15))<<3];
      #pragma unroll
      for (int ni=0;ni<4;++ni) bf[ni] = *(const short8*)&lsB[(size_t)((ch<<7) + wn + (ni<<4) + (lane&15))<<3];
      #pragma unroll
      for (int mi=0;mi<4;++mi)
        #pragma unroll
        for (int ni=0;ni<4;++ni)
          acc[mi][ni] = __builtin_amdgcn_mfma_f32_16x16x32_bf16(af[mi], bf[ni], acc[mi][ni], 0,0,0);
    }
  }
  const long zc = (long)z*zC;
  #pragma unroll
  for (int mi=0;mi<4;++mi){
    #pragma unroll
    for (int ni=0;ni<4;++ni){
      const int col = bn + wn + (ni<<4) + (lane&15);
      const int row0 = bm + wm + (mi<<4) + ((lane>>4)<<2);
      float bv = 0.f;
      if (FLAGS & GF_BIAS){ if (!(FLAGS & GF_BIG) || col < TH_) bv = bias[col]; }
      #pragma unroll
      for (int q=0;q<4;++q){
        const int row = row0 + q;
        float xv = acc[mi][ni][q] + bv;
        if (FLAGS & GF_ADDY) xv += addy[(size_t)(row&255)*lday + col];
        if (FLAGS & GF_TANH) xv = tanh_fast(xv);
        if (FLAGS & GF_BIG){
          if (col < TH_) Cb[(size_t)row*TH_ + col] = f2b(xv);
          else {
            const int c2 = col - TH_;
            const float u = xv + b2f(chkbase[(size_t)row*H_ + c2]);
            chkhid[(size_t)row*H_ + c2] = f2b(tanh_fast(u));
          }
        } else {
          if (FLAGS & GF_WF32)  Cf[zc + (size_t)row*ldC + col] = xv;
          if (FLAGS & GF_WBF16) Cb[zc + (size_t)row*ldC + col] = f2b(xv);
        }
      }
    }
  }
}

// ---------------- persistent bi-GRU encoder ----------------
// 64 blocks = (2 dirs) x (32 j-tiles of 16 hidden units). Weight slice lives in
// registers as MFMA B-fragments for all 128 steps. h exchanged via double-buffered
// global bf16 hi+lo pairs, per-dir spin barrier (device-scope atomics).
__global__ __launch_bounds__(256,1)
void enc_persist(const float* __restrict__ Wf, const float* __restrict__ Wb,
                 const float* __restrict__ bhf, const float* __restrict__ bhb,
                 const ushort* __restrict__ gif, const ushort* __restrict__ gib,
                 ushort* __restrict__ hG, uint* __restrict__ cnt,
                 ushort* __restrict__ encout, ushort* __restrict__ encoutT,
                 float* __restrict__ hTf, float* __restrict__ hTb)
{
  const int g = blockIdx.x;
  const int dir = g >> 5;
  const int j0 = (g & 31) << 4;
  const int tid = threadIdx.x;
  const int w = tid >> 6, lane = tid & 63;
  const int mi = w & 1, kh = w >> 1;
  const int l15 = lane & 15, l4 = lane >> 4;
  const int brow0 = mi*16 + l4*4;

  const float* W = dir ? Wb : Wf;
  const float* bh = dir ? bhb : bhf;
  const ushort* gi = dir ? gib : gif;

  __shared__ __align__(16) ushort hlds[32*1048];   // [32 rows][512 hi | 512 lo | 24 pad]
  __shared__ __align__(16) float cred[2][3][256];
  __shared__ float bhl[48];

  // preload B-fragments (weight slice, bf16) into registers: 3 gates x 8 k-steps
  short8 bw[3][8];
  {
    const int kbase = kh*256 + l4*8;
    #pragma unroll
    for (int ni=0; ni<3; ++ni){
      const float* wr = W + (size_t)(ni*512 + j0 + l15)*512 + kbase;
      #pragma unroll
      for (int ks=0; ks<8; ++ks){
        const float4 f0 = *(const float4*)(wr + ks*32);
        const float4 f1 = *(const float4*)(wr + ks*32 + 4);
        short8 v;
        v[0]=(short)f2b(f0.x); v[1]=(short)f2b(f0.y); v[2]=(short)f2b(f0.z); v[3]=(short)f2b(f0.w);
        v[4]=(short)f2b(f1.x); v[5]=(short)f2b(f1.y); v[6]=(short)f2b(f1.z); v[7]=(short)f2b(f1.w);
        bw[ni][ks] = v;
      }
    }
  }
  if (tid < 48) bhl[tid] = bh[(tid>>4)*512 + j0 + (tid&15)];
  __syncthreads();

  float bh0r=0.f, bh1r=0.f, bh2r=0.f;
  if (kh==0){ bh0r = bhl[l15]; bh1r = bhl[16+l15]; bh2r = bhl[32+l15]; }
  float holdr[4] = {0.f,0.f,0.f,0.f};

  for (int t=0; t<128; ++t){
    const int tt = dir ? (127 - t) : t;
    // stage h (hi+lo) into LDS
    {
      const ushort* src = hG + ((size_t)((t&1)*2 + dir))*32*1024;
      for (int c = tid; c < 4096; c += 256){
        const int row = c >> 7, col = (c & 127) << 3;
        *(uint4*)&hlds[row*1048 + col] = *(const uint4*)&src[row*1024 + col];
      }
    }
    __syncthreads();
    f32x4 acc[3]; acc[0]=0.f; acc[1]=0.f; acc[2]=0.f;
    const int arow = (mi*16 + l15)*1048 + kh*256 + l4*8;
    #pragma unroll
    for (int ks=0; ks<8; ++ks){
      const short8 ah = *(const short8*)&hlds[arow + ks*32];
      const short8 al = *(const short8*)&hlds[arow + 512 + ks*32];
      acc[0] = __builtin_amdgcn_mfma_f32_16x16x32_bf16(ah, bw[0][ks], acc[0],0,0,0);
      acc[1] = __builtin_amdgcn_mfma_f32_16x16x32_bf16(ah, bw[1][ks], acc[1],0,0,0);
      acc[2] = __builtin_amdgcn_mfma_f32_16x16x32_bf16(ah, bw[2][ks], acc[2],0,0,0);
      acc[0] = __builtin_amdgcn_mfma_f32_16x16x32_bf16(al, bw[0][ks], acc[0],0,0,0);
      acc[1] = __builtin_amdgcn_mfma_f32_16x16x32_bf16(al, bw[1][ks], acc[1],0,0,0);
      acc[2] = __builtin_amdgcn_mfma_f32_16x16x32_bf16(al, bw[2][ks], acc[2],0,0,0);
    }
    if (kh==1){
      #pragma unroll
      for (int ni=0; ni<3; ++ni) *(f32x4*)&cred[mi][ni][lane*4] = acc[ni];
    }
    __syncthreads();
    if (kh==0){
      #pragma unroll
      for (int ni=0; ni<3; ++ni){
        const f32x4 o = *(const f32x4*)&cred[mi][ni][lane*4];
        acc[ni][0]+=o[0]; acc[ni][1]+=o[1]; acc[ni][2]+=o[2]; acc[ni][3]+=o[3];
      }
      ushort* dst = hG + ((size_t)(((t+1)&1)*2 + dir))*32*1024;
      const ushort* girow = gi + ((size_t)tt*32 + brow0)*1536 + j0 + l15;
      #pragma unroll
      for (int q=0; q<4; ++q){
        const int b = brow0 + q;
        const float gi0 = b2f(girow[q*1536]);
        const float gi1 = b2f(girow[q*1536 + 512]);
        const float gi2 = b2f(girow[q*1536 + 1024]);
        const float r  = sigf(gi0 + acc[0][q] + bh0r);
        const float zg = sigf(gi1 + acc[1][q] + bh1r);
        const float n  = tanh_fast(gi2 + r*(acc[2][q] + bh2r));
        const float h2 = (1.f - zg)*n + zg*holdr[q];
        holdr[q] = h2;
        const ushort hb = f2b(h2);
        const ushort hl = f2b(h2 - b2f(hb));
        dst[(size_t)b*1024 + j0 + l15] = hb;
        dst[(size_t)b*1024 + 512 + j0 + l15] = hl;
        encout[((size_t)b*SIN_ + tt)*1024 + dir*H_ + j0 + l15] = hb;
        encoutT[((size_t)b*1024 + dir*H_ + j0 + l15)*SIN_ + tt] = hb;
      }
    }
    __syncthreads();
    if (t < 127){
      if (tid == 0){
        __threadfence();
        __hip_atomic_fetch_add(&cnt[dir*128 + t], 1u, __ATOMIC_RELEASE, __HIP_MEMORY_SCOPE_AGENT);
        while (__hip_atomic_load(&cnt[dir*128 + t], __ATOMIC_RELAXED, __HIP_MEMORY_SCOPE_AGENT) < 32u)
          __builtin_amdgcn_s_sleep(1);
        (void)__hip_atomic_load(&cnt[dir*128 + t], __ATOMIC_ACQUIRE, __HIP_MEMORY_SCOPE_AGENT);
      }
      __syncthreads();
    }
  }
  if (kh==0){
    float* hT = dir ? hTb : hTf;
    #pragma unroll
    for (int q=0; q<4; ++q) hT[(size_t)(brow0+q)*H_ + j0 + l15] = holdr[q];
  }
}

// embsum = bf16(emb + trans)
__global__ void k_embsum(const ushort* __restrict__ embxs, const float* __restrict__ transo,
                         ushort* __restrict__ esum)
{
  for (long i = (long)blockIdx.x*blockDim.x + threadIdx.x; i < (long)B_*SIN_*E_; i += (long)gridDim.x*blockDim.x){
    int e = (int)(i & 255); long bs = i >> 8; int s = (int)(bs & 127); int bb = (int)(bs >> 7);
    esum[i] = f2b(b2f(embxs[((size_t)s*B_ + bb)*E_ + e]) + transo[i]);
  }
}

// row softmax over SIN=128, one wave per row
__global__ __launch_bounds__(256) void k_softmax(const float* __restrict__ sc, ushort* __restrict__ al)
{
  const int row = blockIdx.x*4 + (threadIdx.x>>6);
  const int lane = threadIdx.x&63;
  const float* s = sc + (size_t)row*SIN_;
  const float2 v = *(const float2*)&s[lane*2];
  float m = fmaxf(v.x, v.y);
  #pragma unroll
  for (int o=1;o<64;o<<=1) m = fmaxf(m, __shfl_xor(m, o));
  const float e0 = __expf(v.x - m), e1 = __expf(v.y - m);
  float sum = e0 + e1;
  #pragma unroll
  for (int o=1;o<64;o<<=1) sum += __shfl_xor(sum, o);
  const float inv = 1.f/sum;
  ushort* a = al + (size_t)row*SIN_;
  const uint pkv = (uint)f2b(e0*inv) | ((uint)f2b(e1*inv)<<16);
  *(uint*)&a[lane*2] = pkv;
}

// h0_dec = tanh(hidden_cat @ merge_W^T + merge_b), with the reference's odd reshape
__global__ __launch_bounds__(512)
void k_merge(const float* __restrict__ hTf, const float* __restrict__ hTb,
             const float* __restrict__ mW, const float* __restrict__ mb,
             float* __restrict__ h0)
{
  const int b = blockIdx.x, j = threadIdx.x;
  __shared__ float hc[1024];
  for (int i=j; i<1024; i+=512){
    const int half = i >> 9, jj = i & 511;
    hc[i] = (b < 16) ? hTf[(size_t)(2*b + half)*H_ + jj] : hTb[(size_t)(2*(b-16) + half)*H_ + jj];
  }
  __syncthreads();
  float d = mb[j];
  const float* wr = mW + (size_t)j*1024;
  #pragma unroll 8
  for (int k=0;k<1024;k+=4){
    const float4 a = *(const float4*)&wr[k];
    const float4 hh = *(const float4*)&hc[k];
    d += a.x*hh.x + a.y*hh.y + a.z*hh.z + a.w*hh.w;
  }
  h0[(size_t)b*H_ + j] = tanh_fast(d);
}

__global__ void k_bcast(const float* __restrict__ h0, float* __restrict__ hf, ushort* __restrict__ hb)
{
  for (long i = (long)blockIdx.x*blockDim.x + threadIdx.x; i < (long)8192*H_; i += (long)gridDim.x*blockDim.x){
    const int jj = (int)(i & 511); const long row = i >> 9; const int bb = (int)(row >> 8);
    const float v = h0[(size_t)bb*H_ + jj];
    hf[i] = v; hb[i] = f2b(v);
  }
}

// ---------------- decoder gates + logits ----------------
__global__ __launch_bounds__(256)
void dec_gates(const ushort* __restrict__ gh, const ushort* __restrict__ gib,
               const float* __restrict__ hin, const float* __restrict__ sp_t,
               const float* __restrict__ wchk, const float* __restrict__ checked,
               const float* __restrict__ decW, int t,
               float* __restrict__ hout, ushort* __restrict__ h2b,
               float* __restrict__ logits)
{
  const int tid = threadIdx.x;
  const int row = blockIdx.x*32 + (tid>>3);
  const int bb = row>>8, yy = row&255;
  const int j0 = (tid&7)<<6;
  const float ck = checked[((size_t)bb*33 + t)*Y_ + yy];
  const ushort* ghr = gh + (size_t)row*TH_;
  const ushort* gir = gib + (size_t)row*TH_;
  const float* hr = hin + (size_t)row*H_;
  const float* sp = sp_t + (size_t)bb*TH_;
  float* ho = hout + (size_t)row*H_;
  ushort* hbw = h2b + (size_t)row*H_;
  float lacc = 0.f;
  for (int c8=0;c8<8;++c8){
    const int j = j0 + (c8<<3);
    const uint4 g0 = *(const uint4*)&ghr[j];
    const uint4 g1 = *(const uint4*)&ghr[H_+j];
    const uint4 g2 = *(const uint4*)&ghr[2*H_+j];
    const uint4 i0 = *(const uint4*)&gir[j];
    const uint4 i1 = *(const uint4*)&gir[H_+j];
    const uint4 i2 = *(const uint4*)&gir[2*H_+j];
    const float4 hv0 = *(const float4*)&hr[j];
    const float4 hv1 = *(const float4*)&hr[j+4];
    const float4 sr0 = *(const float4*)&sp[j],        sr1 = *(const float4*)&sp[j+4];
    const float4 sz0 = *(const float4*)&sp[H_+j],     sz1 = *(const float4*)&sp[H_+j+4];
    const float4 sn0 = *(const float4*)&sp[2*H_+j],   sn1 = *(const float4*)&sp[2*H_+j+4];
    const float4 wr0 = *(const float4*)&wchk[j],      wr1 = *(const float4*)&wchk[j+4];
    const float4 wz0 = *(const float4*)&wchk[H_+j],   wz1 = *(const float4*)&wchk[H_+j+4];
    const float4 wn0 = *(const float4*)&wchk[2*H_+j], wn1 = *(const float4*)&wchk[2*H_+j+4];
    const float4 dw0 = *(const float4*)&decW[j],      dw1 = *(const float4*)&decW[j+4];
    const float hva[8] = {hv0.x,hv0.y,hv0.z,hv0.w,hv1.x,hv1.y,hv1.z,hv1.w};
    const float sra[8] = {sr0.x,sr0.y,sr0.z,sr0.w,sr1.x,sr1.y,sr1.z,sr1.w};
    const float sza[8] = {sz0.x,sz0.y,sz0.z,sz0.w,sz1.x,sz1.y,sz1.z,sz1.w};
    const float sna[8] = {sn0.x,sn0.y,sn0.z,sn0.w,sn1.x,sn1.y,sn1.z,sn1.w};
    const float wra[8] = {wr0.x,wr0.y,wr0.z,wr0.w,wr1.x,wr1.y,wr1.z,wr1.w};
    const float wza[8] = {wz0.x,wz0.y,wz0.z,wz0.w,wz1.x,wz1.y,wz1.z,wz1.w};
    const float wna[8] = {wn0.x,wn0.y,wn0.z,wn0.w,wn1.x,wn1.y,wn1.z,wn1.w};
    const float dwa[8] = {dw0.x,dw0.y,dw0.z,dw0.w,dw1.x,dw1.y,dw1.z,dw1.w};
    const ushort* p0 = (const ushort*)&g0;
    const ushort* p1 = (const ushort*)&g1;
    const ushort* p2 = (const ushort*)&g2;
    const ushort* p3 = (const ushort*)&i0;
    const ushort* p4 = (const ushort*)&i1;
    const ushort* p5 = (const ushort*)&i2;
    float h2a[8];
    uint pk[4] = {0u,0u,0u,0u};
    #pragma unroll
    for (int e=0;e<8;++e){
      const float gn_ = b2f(p2[e]);
      const float xr = b2f(p3[e]) + sra[e] + ck*wra[e] + b2f(p0[e]);
      const float xz = b2f(p4[e]) + sza[e] + ck*wza[e] + b2f(p1[e]);
      const float xn = b2f(p5[e]) + sna[e] + ck*wna[e];
      const float r  = sigf(xr);
      const float zg = sigf(xz);
      const float n  = tanh_fast(xn + r*gn_);
      const float h2 = (1.f - zg)*n + zg*hva[e];
      h2a[e] = h2;
      pk[e>>1] |= ((uint)f2b(h2)) << ((e&1)<<4);
      lacc += h2 * dwa[e];
    }
    *(float4*)&ho[j]   = make_float4(h2a[0],h2a[1],h2a[2],h2a[3]);
    *(float4*)&ho[j+4] = make_float4(h2a[4],h2a[5],h2a[6],h2a[7]);
    *(uint4*)&hbw[j]   = make_uint4(pk[0],pk[1],pk[2],pk[3]);
  }
  lacc += __shfl_xor(lacc, 1);
  lacc += __shfl_xor(lacc, 2);
  lacc += __shfl_xor(lacc, 4);
  if ((tid&7)==0) logits[row] = lacc;
}

// ---------------- per-step losses ----------------
__global__ __launch_bounds__(256)
void dec_loss(const ushort* __restrict__ chkhid, const float* __restrict__ cw2,
              const float* __restrict__ cb2v, const float* __restrict__ checked,
              const float* __restrict__ yv, const float* __restrict__ logits,
              int t, float* __restrict__ acc)
{
  const int tid = threadIdx.x;
  if (blockIdx.x < 64){
    const int wv = tid>>6, lane = tid&63;
    const float4 w20 = *(const float4*)&cw2[lane*8];
    const float4 w21 = *(const float4*)&cw2[lane*8+4];
    const float w2a[8] = {w20.x,w20.y,w20.z,w20.w,w21.x,w21.y,w21.z,w21.w};
    const float bb2 = cb2v[0];
    float wsum = 0.f;
    for (int i=0;i<32;++i){
      const int row = blockIdx.x*128 + wv*32 + i;
      const uint4 hv = *(const uint4*)&chkhid[(size_t)row*H_ + lane*8];
      const ushort* ph = (const ushort*)&hv;
      float p = 0.f;
      #pragma unroll
      for (int e=0;e<8;++e) p += b2f(ph[e]) * w2a[e];
      #pragma unroll
      for (int o=1;o<64;o<<=1) p += __shfl_xor(p, o);
      if (lane==0){
        const int bb = row>>8, yy = row&255;
        const float u = p + bb2;
        const float c = checked[((size_t)bb*33 + (t+1))*Y_ + yy];
        const float yt = yv[((size_t)bb*SOUT_ + t)*Y_ + yy];
        wsum += yt * (c*splus(-u) + (1.f-c)*splus(u));
      }
    }
    if (lane==0) atomicAdd(acc+1, wsum);
  } else {
    __shared__ float red[256];
    __shared__ float bmx[32], bsm[32];
    const int bb = tid>>3, part = tid&7;
    float lv[32];
    const float* lg = logits + bb*Y_ + part*32;
    float m = -1e30f;
    #pragma unroll
    for (int i=0;i<32;++i){ lv[i] = lg[i]; m = fmaxf(m, lv[i]); }
    red[tid] = m; __syncthreads();
    if (part==0){ float mm = red[tid];
      #pragma unroll
      for (int k2=1;k2<8;++k2) mm = fmaxf(mm, red[tid+k2]);
      bmx[bb] = mm; }
    __syncthreads();
    const float bm = bmx[bb];
    float se = 0.f;
    #pragma unroll
    for (int i=0;i<32;++i) se += __expf(lv[i]-bm);
    red[tid] = se; __syncthreads();
    if (part==0){ float ss = 0.f;
      #pragma unroll
      for (int k2=0;k2<8;++k2) ss += red[tid+k2];
      bsm[bb] = ss; }
    __syncthreads();
    const float lse = bm + logf(bsm[bb]);
    const float* yr = yv + ((size_t)bb*SOUT_ + t)*Y_ + part*32;
    float pl = 0.f;
    #pragma unroll
    for (int i=0;i<32;++i) pl += yr[i]*(lv[i]-lse);
    red[tid] = pl; __syncthreads();
    if (tid==0){ float s = 0.f;
      for (int k2=0;k2<256;++k2) s += red[k2];
      atomicAdd(acc+0, -s); }
  }
}

__global__ void k_final(const float* __restrict__ acc, float* __restrict__ out)
{
  if (threadIdx.x==0){
    const float ls = acc[0], cls = acc[1], ys = acc[2];
    out[0] = (ls+cls)/ys; out[1] = ls/ys; out[2] = cls/ys;
  }
}

// ---------------- host ----------------
extern "C" void kernel_launch(void* const* d_in, const int* in_sizes, int n_in,
                              void* d_out, int out_size, void* d_ws, size_t ws_size,
                              hipStream_t stream)
{
  (void)in_sizes; (void)n_in; (void)out_size;
  const int*   x      = (const int*)d_in[0];
  const int*   akey   = (const int*)d_in[1];
  const int*   atype  = (const int*)d_in[2];
  const int*   croom  = (const int*)d_in[3];
  const float* checked= (const float*)d_in[4];
  const float* yv     = (const float*)d_in[5];
  const float* emb    = (const float*)d_in[6];
  const float* attab  = (const float*)d_in[7];
  const float* eWihF  = (const float*)d_in[8];
  const float* eWhhF  = (const float*)d_in[9];
  const float* ebihF  = (const float*)d_in[10];
  const float* ebhhF  = (const float*)d_in[11];
  const float* eWihB  = (const float*)d_in[12];
  const float* eWhhB  = (const float*)d_in[13];
  const float* ebihB  = (const float*)d_in[14];
  const float* ebhhB  = (const float*)d_in[15];
  const float* transW = (const float*)d_in[16];
  const float* transb = (const float*)d_in[17];
  const float* mergeW = (const float*)d_in[18];
  const float* mergeb = (const float*)d_in[19];
  const float* dWih   = (const float*)d_in[20];
  const float* dWhh   = (const float*)d_in[21];
  const float* dbih   = (const float*)d_in[22];
  const float* dbhh   = (const float*)d_in[23];
  const float* dW     = (const float*)d_in[24];
  const float* cW1    = (const float*)d_in[26];
  const float* cb1    = (const float*)d_in[27];
  const float* cW2    = (const float*)d_in[28];
  const float* cb2    = (const float*)d_in[29];

  char* base = (char*)d_ws;
  size_t off = 0;
  auto alloc = [&](size_t bytes)->char*{ char* p = base + off; off += (bytes + 255) & ~(size_t)255; return p; };

  float*  accv   = (float*)alloc(256);
  ushort* embxs  = (ushort*)alloc((size_t)SIN_*B_*E_*2);
  ushort* aemb   = (ushort*)alloc((size_t)Y_*E_*2);
  ushort* aembT  = (ushort*)alloc((size_t)Y_*E_*2);
  float*  avec   = (float*)alloc((size_t)Y_*32*4);
  ushort* yprev  = (ushort*)alloc((size_t)SOUT_*B_*Y_*2);
  ushort* acat   = (ushort*)alloc((size_t)SOUT_*B_*512*2);
  ushort* gi_fb  = (ushort*)alloc((size_t)2*SIN_*B_*TH_*2);   // gi_f | gi_b ; later aliased by gi_base (exact size)
  ushort* gi_f   = gi_fb;
  ushort* gi_b   = gi_fb + (size_t)SIN_*B_*TH_;
  ushort* gibase = gi_fb;
  ushort* encout = (ushort*)alloc((size_t)B_*SIN_*1024*2);    // + encoutT region reused as hbuf0
  ushort* encoutT= (ushort*)alloc((size_t)B_*1024*SIN_*2);
  float*  hbuf0  = (float*)encout;                            // 8192*512*4 == encout+encoutT exactly
  float*  hTf    = (float*)alloc((size_t)B_*H_*4);
  float*  hTb    = (float*)alloc((size_t)B_*H_*4);
  float*  h0dec  = (float*)alloc((size_t)B_*H_*4);
  float*  transo = (float*)alloc((size_t)B_*SIN_*E_*4);       // start of region reused as gh
  ushort* esum   = (ushort*)alloc((size_t)B_*SIN_*E_*2);
  float*  scores = (float*)alloc((size_t)B_*Y_*SIN_*4);
  ushort* alpha  = (ushort*)alloc((size_t)B_*Y_*SIN_*2);
  ushort* att    = (ushort*)alloc((size_t)8192*1024*2);
  ushort* gh     = (ushort*)transo;                           // 25.2MB <= transo..att region (29.3MB)
  ushort* chkbase= (ushort*)alloc((size_t)8192*H_*2);
  float*  addy   = (float*)alloc((size_t)Y_*TH_*4);
  float*  addcy  = (float*)alloc((size_t)Y_*H_*4);
  float*  sproj  = (float*)alloc((size_t)SOUT_*B_*TH_*4);
  float*  wchk   = (float*)alloc((size_t)TH_*4);
  ushort* WihFb  = (ushort*)alloc((size_t)TH_*E_*2);
  ushort* WihBb  = (ushort*)alloc((size_t)TH_*E_*2);
  ushort* Wtrb   = (ushort*)alloc((size_t)E_*1024*2);
  ushort* Wattb  = (ushort*)alloc((size_t)TH_*1024*2);
  ushort* Wcat2b = (ushort*)alloc((size_t)TH_*512*2);
  ushort* W1attb = (ushort*)alloc((size_t)H_*1024*2);
  ushort* Wbigb  = (ushort*)alloc((size_t)2048*512*2);
  float*  hbuf1  = (float*)alloc((size_t)8192*H_*4);
  ushort* h2b    = (ushort*)alloc((size_t)8192*H_*2);
  ushort* chkhid = (ushort*)alloc((size_t)8192*H_*2);
  float*  logits = (float*)alloc((size_t)8192*4);
  ushort* hG     = (ushort*)alloc((size_t)2*2*32*1024*2);     // h exchange: [buf][dir][b][hi512|lo512]
  uint*   cnt    = (uint*)alloc((size_t)256*4);

  if (off > ws_size){ k_wsfail<<<1,1,0,stream>>>((float*)d_out); return; }

  float* outp = (float*)d_out;

  k_init<<<dim3(1), dim3(64), 0, stream>>>(accv);
  k_init_enc<<<dim3(64), dim3(256), 0, stream>>>(cnt, hG);
  k_ysum<<<dim3(256), dim3(256), 0, stream>>>(yv, accv);
  k_lookup<<<dim3(2048), dim3(256), 0, stream>>>(x, akey, atype, croom, yv, emb, attab,
                                                 embxs, aemb, aembT, avec, acat, yprev);
  auto conv = [&](const float* s, ushort* d, int r, int c, int sld, int dld, int doff){
    k_conv<<<dim3(512), dim3(256), 0, stream>>>(s, d, r, c, sld, dld, doff);
  };
  conv(eWihF, WihFb, TH_, E_, E_, E_, 0);
  conv(eWihB, WihBb, TH_, E_, E_, E_, 0);
  conv(transW, Wtrb, E_, 1024, 1024, 1024, 0);
  conv(dWih, Wattb, TH_, 1024, 1569, 1024, 0);
  conv(dWih+1025, Wcat2b, TH_, 256, 1569, 512, 0);
  conv(dWih+1313, Wcat2b, TH_, 256, 1569, 512, 256);
  conv(cW1, W1attb, H_, 1024, 1568, 1024, 0);
  conv(dWhh, Wbigb, TH_, 512, 512, 512, 0);
  conv(cW1+1056, Wbigb + (size_t)TH_*512, H_, 512, 1568, 512, 0);
  k_prep2<<<dim3(1024), dim3(256), 0, stream>>>(avec, dWih, dbih, cW1, cb1, addy, addcy, wchk);

  // encoder input projections (bias folded in)
  gemm_nt<(GF_BIAS|GF_WBF16)><<<dim3(12,32,1), dim3(256), 0, stream>>>(
    embxs, WihFb, ebihF, nullptr, 0, nullptr, gi_f, TH_, E_, E_, E_, 0, 0L,0L,0L, nullptr, nullptr);
  gemm_nt<(GF_BIAS|GF_WBF16)><<<dim3(12,32,1), dim3(256), 0, stream>>>(
    embxs, WihBb, ebihB, nullptr, 0, nullptr, gi_b, TH_, E_, E_, E_, 0, 0L,0L,0L, nullptr, nullptr);

  enc_persist<<<dim3(64), dim3(256), 0, stream>>>(eWhhF, eWhhB, ebhhF, ebhhB, gi_f, gi_b,
                                                  hG, cnt, encout, encoutT, hTf, hTb);

  // trans_out = tanh(enc_out @ trans_W^T + b)
  gemm_nt<(GF_BIAS|GF_TANH|GF_WF32)><<<dim3(2,32,1), dim3(256), 0, stream>>>(
    encout, Wtrb, transb, nullptr, 0, transo, nullptr, E_, 1024, 1024, 1024, 0, 0L,0L,0L, nullptr, nullptr);
  k_embsum<<<dim3(1024), dim3(256), 0, stream>>>(embxs, transo, esum);

  // scores[b] = action_emb @ embsum_b^T  (batched over b)
  gemm_nt<GF_WF32><<<dim3(1,2,32), dim3(256), 0, stream>>>(
    aemb, esum, nullptr, nullptr, 0, scores, nullptr, SIN_, E_, E_, E_, 0,
    0L, (long)SIN_*E_, (long)Y_*SIN_, nullptr, nullptr);
  k_softmax<<<dim3(2048), dim3(256), 0, stream>>>(scores, alpha);

  // attention[b] = alpha_b @ enc_out_b   (W = enc_outT_b)
  gemm_nt<GF_WBF16><<<dim3(8,2,32), dim3(256), 0, stream>>>(
    alpha, encoutT, nullptr, nullptr, 0, nullptr, att, 1024, SIN_, SIN_, SIN_, 0,
    (long)Y_*SIN_, (long)1024*SIN_, (long)Y_*1024, nullptr, nullptr);

  k_merge<<<dim3(32), dim3(512), 0, stream>>>(hTf, hTb, mergeW, mergeb, h0dec);

  // yemb -> acat[:,256:512]
  gemm_nt<GF_WBF16><<<dim3(2,8,1), dim3(256), 0, stream>>>(
    yprev, aembT, nullptr, nullptr, 0, nullptr, acat+256, 512, Y_, Y_, Y_, 0, 0L,0L,0L, nullptr, nullptr);
  // sproj = acat @ Wcat2^T  (room + y parts of dec_Wih, all 32 steps)
  gemm_nt<GF_WF32><<<dim3(12,8,1), dim3(256), 0, stream>>>(
    acat, Wcat2b, nullptr, nullptr, 0, sproj, nullptr, TH_, 512, 512, 512, 0, 0L,0L,0L, nullptr, nullptr);

  // gi_base = att @ W_att^T + add_y[y]   ;  chk_base = att @ W1_att^T + addc_y[y]
  gemm_nt<(GF_WBF16|GF_ADDY)><<<dim3(12,64,1), dim3(256), 0, stream>>>(
    att, Wattb, nullptr, addy, TH_, nullptr, gibase, TH_, 1024, 1024, 1024, 0, 0L,0L,0L, nullptr, nullptr);
  gemm_nt<(GF_WBF16|GF_ADDY)><<<dim3(4,64,1), dim3(256), 0, stream>>>(
    att, W1attb, nullptr, addcy, H_, nullptr, chkbase, H_, 1024, 1024, 1024, 0, 0L,0L,0L, nullptr, nullptr);

  k_bcast<<<dim3(4096), dim3(256), 0, stream>>>(h0dec, hbuf0, h2b);

  // prologue: gh for t=0
  gemm_nt<(GF_BIG|GF_BIAS)><<<dim3(12,64,1), dim3(256), 0, stream>>>(
    h2b, Wbigb, dbhh, nullptr, 0, nullptr, gh, TH_, H_, H_, H_, 0, 0L,0L,0L, chkbase, chkhid);

  for (int t=0; t<SOUT_; ++t){
    float* hin  = (t&1) ? hbuf1 : hbuf0;
    float* hout = (t&1) ? hbuf0 : hbuf1;
    dec_gates<<<dim3(256), dim3(256), 0, stream>>>(gh, gibase, hin, sproj + (size_t)t*B_*TH_,
                                                   wchk, checked, dW, t, hout, h2b, logits);
    if (t < SOUT_-1){
      gemm_nt<(GF_BIG|GF_BIAS)><<<dim3(16,64,1), dim3(256), 0, stream>>>(
        h2b, Wbigb, dbhh, nullptr, 0, nullptr, gh, TH_, H_, H_, H_, 0, 0L,0L,0L, chkbase, chkhid);
    } else {
      gemm_nt<(GF_BIG|GF_BIAS)><<<dim3(4,64,1), dim3(256), 0, stream>>>(
        h2b, Wbigb, dbhh, nullptr, 0, nullptr, gh, TH_, H_, H_, H_, TH_, 0L,0L,0L, chkbase, chkhid);
    }
    dec_loss<<<dim3(65), dim3(256), 0, stream>>>(chkhid, cW2, cb2, checked, yv, logits, t, accv);
  }
  k_final<<<dim3(1), dim3(1), 0, stream>>>(accv, outp);
}

// Round 3
// 5905.445 us; speedup vs baseline: 3.1435x; 1.5467x over previous
//
#include <hip/hip_runtime.h>

typedef unsigned short ushort;
typedef unsigned int uint;
typedef __attribute__((ext_vector_type(8))) short short8;
typedef __attribute__((ext_vector_type(4))) float f32x4;
typedef __attribute__((ext_vector_type(4))) uint u32x4;

#define DEVI __device__ __forceinline__

#define B_ 32
#define SIN_ 128
#define SOUT_ 32
#define Y_ 256
#define H_ 512
#define E_ 256
#define TH_ 1536

DEVI float b2f(ushort u){ return __uint_as_float(((uint)u)<<16); }
DEVI ushort f2b(float f){ uint x = __float_as_uint(f); return (ushort)((x + 0x7FFFu + ((x>>16)&1u)) >> 16); }
DEVI float sigf(float x){ return 1.f/(1.f+__expf(-x)); }
DEVI float tanh_fast(float x){ return 2.f/(1.f+__expf(-2.f*x)) - 1.f; }
DEVI float splus(float x){ return fmaxf(x,0.f) + log1pf(__expf(-fabsf(x))); }
DEVI short8 cvt8(u32x4 v){ return __builtin_bit_cast(short8, v); }

// sc0 sc1 = coherent through Infinity Cache (cross-XCD visible without fences)
DEVI uint ld_flag(const uint* p){
  uint r;
  asm volatile("global_load_dword %0, %1, off sc0 sc1\n\ts_waitcnt vmcnt(0)"
               : "=v"(r) : "v"(p) : "memory");
  return r;
}
DEVI void st_flag(uint* p, uint v){
  asm volatile("global_store_dword %0, %1, off sc0 sc1" :: "v"(p), "v"(v) : "memory");
}
DEVI void st_h16(ushort* p, uint v){
  asm volatile("global_store_short %0, %1, off sc0 sc1" :: "v"(p), "v"(v) : "memory");
}

// ---------------- init / reductions ----------------
__global__ void k_init(float* acc){ if (threadIdx.x < 4) acc[threadIdx.x] = 0.f; }

__global__ void k_wsfail(float* out){ out[0]=1.2345e8f; out[1]=2.3456e8f; out[2]=3.4567e8f; }

// zero flags + h exchange buffers
__global__ void k_init_enc(uint* __restrict__ flags, ushort* __restrict__ hG)
{
  const int id = blockIdx.x*256 + threadIdx.x;
  if (id < 256) flags[id] = 0u;
  // hG: 2 buf * 2 dir * 32 * 1024 ushorts = 131072 ushorts = 16384 uint4
  if (id < 16384) ((uint4*)hG)[id] = make_uint4(0,0,0,0);
}

__global__ __launch_bounds__(256) void k_ysum(const float* __restrict__ yv, float* __restrict__ acc)
{
  __shared__ float red[256];
  float s = 0.f;
  for (long i = (long)blockIdx.x*256 + threadIdx.x; i < (long)B_*SOUT_*Y_; i += (long)gridDim.x*256) s += yv[i];
  red[threadIdx.x] = s; __syncthreads();
  for (int o=128;o;o>>=1){ if ((int)threadIdx.x<o) red[threadIdx.x] += red[threadIdx.x+o]; __syncthreads(); }
  if (threadIdx.x==0) atomicAdd(acc+2, red[0]);
}

// ---------------- embedding / lookup ----------------
__global__ void k_lookup(const int* __restrict__ x, const int* __restrict__ akey,
                         const int* __restrict__ atype, const int* __restrict__ croom,
                         const float* __restrict__ yv,
                         const float* __restrict__ emb, const float* __restrict__ attab,
                         ushort* __restrict__ embxs, ushort* __restrict__ aemb,
                         ushort* __restrict__ aembT, float* __restrict__ avec,
                         ushort* __restrict__ acat, ushort* __restrict__ yprev)
{
  const long N1 = (long)SIN_*B_*E_;
  const long N2 = (long)Y_*E_;
  const long N3 = (long)Y_*32;
  const long N4 = (long)SOUT_*B_*E_;
  const long N5 = (long)SOUT_*B_*Y_;
  for (long i = (long)blockIdx.x*blockDim.x + threadIdx.x; i < N1+N2+N3+N4+N5; i += (long)gridDim.x*blockDim.x){
    long id = i;
    if (id < N1){
      int e = id & 255; long sb = id >> 8; int bb = (int)(sb & 31); int s = (int)(sb >> 5);
      embxs[id] = f2b(emb[(size_t)x[bb*SIN_ + s]*E_ + e]);
    } else if ((id -= N1) < N2){
      int e = (int)(id & 255), yy = (int)(id >> 8);
      ushort v = f2b(emb[(size_t)akey[yy]*E_ + e]);
      aemb[yy*E_ + e] = v;
      aembT[e*Y_ + yy] = v;
    } else if ((id -= N2) < N3){
      int a = (int)(id & 31), yy = (int)(id >> 5);
      avec[yy*32 + a] = attab[atype[yy]*32 + a];
    } else if ((id -= N3) < N4){
      int e = (int)(id & 255); long tb = id >> 8; int bb = (int)(tb & 31); int t = (int)(tb >> 5);
      acat[(size_t)tb*512 + e] = f2b(emb[(size_t)croom[bb*SOUT_ + t]*E_ + e]);
    } else { id -= N4;
      int yy = (int)(id & 255); long tb = id >> 8; int bb = (int)(tb & 31); int t = (int)(tb >> 5);
      yprev[id] = (t == 0) ? (ushort)0 : f2b(yv[((size_t)bb*SOUT_ + (t-1))*Y_ + yy]);
    }
  }
}

// generic f32 -> bf16 strided convert
__global__ void k_conv(const float* __restrict__ src, ushort* __restrict__ dst,
                       int rows, int cols, int sld, int dld, int doff)
{
  for (long i = (long)blockIdx.x*blockDim.x + threadIdx.x; i < (long)rows*cols; i += (long)gridDim.x*blockDim.x){
    int c = (int)(i % cols); int r = (int)(i / cols);
    dst[(size_t)r*dld + doff + c] = f2b(src[(size_t)r*sld + c]);
  }
}

// add_y, addc_y, wchk, dbhh_rz (r,z parts of dec_bhh; n part zero)
__global__ void k_prep2(const float* __restrict__ avec, const float* __restrict__ decWih,
                        const float* __restrict__ dbih, const float* __restrict__ cW1,
                        const float* __restrict__ cb1, const float* __restrict__ dbhh,
                        float* __restrict__ addy, float* __restrict__ addcy,
                        float* __restrict__ wchk, float* __restrict__ dbhhrz)
{
  const long NA = (long)Y_*TH_;
  const long NB = (long)Y_*H_;
  for (long i = (long)blockIdx.x*blockDim.x + threadIdx.x; i < NA+NB+TH_+TH_; i += (long)gridDim.x*blockDim.x){
    long id = i;
    if (id < NA){
      int n = (int)(id % TH_), yy = (int)(id / TH_);
      float s = dbih[n];
      const float* wr = decWih + (size_t)n*1569 + 1281;
      const float* av = avec + yy*32;
      #pragma unroll
      for (int a=0;a<32;++a) s += av[a]*wr[a];
      addy[id] = s;
    } else if ((id -= NA) < NB){
      int n = (int)(id & 511), yy = (int)(id >> 9);
      float s = cb1[n];
      const float* wr = cW1 + (size_t)n*1568 + 1024;
      const float* av = avec + yy*32;
      #pragma unroll
      for (int a=0;a<32;++a) s += av[a]*wr[a];
      addcy[id] = s;
    } else if ((id -= NB) < TH_){
      wchk[id] = decWih[(size_t)id*1569 + 1024];
    } else { id -= TH_;
      dbhhrz[id] = (id < 1024) ? dbhh[id] : 0.f;
    }
  }
}

// ---------------- bf16 NT GEMM: C[M,N] = A[M,K] @ W[N,K]^T  (MFMA 16x16x32) ----------------
#define GF_BIAS 1
#define GF_TANH 2
#define GF_WF32 4
#define GF_WBF16 8
#define GF_ADDY 32
#define GF_CHK 64

template<int FLAGS>
__global__ __launch_bounds__(256)
void gemm_nt(const ushort* __restrict__ A, const ushort* __restrict__ W,
             const float* __restrict__ bias,
             const float* __restrict__ addy, int lday,
             float* __restrict__ Cf, ushort* __restrict__ Cb, int ldC,
             int K, int ldA, int ldW, int n0,
             long zA, long zW, long zC,
             const ushort* __restrict__ chkbase, ushort* __restrict__ chkhid)
{
  const int z = blockIdx.z;
  A += (long)z*zA; W += (long)z*zW;
  const int bn = n0 + (blockIdx.x<<7);
  const int bm = (blockIdx.y<<7);
  const int tid = threadIdx.x;
  const int w = tid>>6, lane = tid&63;
  const int wm = (w>>1)<<6, wn = (w&1)<<6;
  const int rs = tid>>1;
  const int kh = (tid&1)<<5;
  __shared__ ushort lsA[8192];
  __shared__ ushort lsB[8192];
  f32x4 acc[4][4];
  #pragma unroll
  for (int i=0;i<4;++i)
    #pragma unroll
    for (int jj=0;jj<4;++jj) acc[i][jj] = 0.f;

  const ushort* pa = A + (size_t)(bm+rs)*ldA + kh;
  const ushort* pb = W + (size_t)(bn+rs)*ldW + kh;
  uint4 va[4], vb[4];
  #pragma unroll
  for (int i=0;i<4;++i){ va[i] = *(const uint4*)(pa + i*8); vb[i] = *(const uint4*)(pb + i*8); }
  const int nkt = K>>6;
  for (int kt=0; kt<nkt; ++kt){
    __syncthreads();
    #pragma unroll
    for (int i=0;i<4;++i){
      const int c = ((tid&1)<<2) + i;
      *(uint4*)&lsA[(size_t)((c<<7) + rs)<<3] = va[i];
      *(uint4*)&lsB[(size_t)((c<<7) + rs)<<3] = vb[i];
    }
    __syncthreads();
    if (kt+1 < nkt){
      const ushort* qa = pa + (size_t)(kt+1)*64;
      const ushort* qb = pb + (size_t)(kt+1)*64;
      #pragma unroll
      for (int i=0;i<4;++i){ va[i] = *(const uint4*)(qa + i*8); vb[i] = *(const uint4*)(qb + i*8); }
    }
    #pragma unroll
    for (int ks=0;ks<2;++ks){
      const int ch = (ks<<2) + (lane>>4);
      short8 af[4], bf[4];
      #pragma unroll
      for (int mi=0;mi<4;++mi) af[mi] = *(const short8*)&lsA[(size_t)((ch<<7) + wm + (mi<<4) + (lane&15))<<3];
      #pragma unroll
      for (int ni=0;ni<4;++ni) bf[ni] = *(const short8*)&lsB[(size_t)((ch<<7) + wn + (ni<<4) + (lane&15))<<3];
      #pragma unroll
      for (int mi=0;mi<4;++mi)
        #pragma unroll
        for (int ni=0;ni<4;++ni)
          acc[mi][ni] = __builtin_amdgcn_mfma_f32_16x16x32_bf16(af[mi], bf[ni], acc[mi][ni], 0,0,0);
    }
  }
  const long zc = (long)z*zC;
  #pragma unroll
  for (int mi=0;mi<4;++mi){
    #pragma unroll
    for (int ni=0;ni<4;++ni){
      const int col = bn + wn + (ni<<4) + (lane&15);
      const int row0 = bm + wm + (mi<<4) + ((lane>>4)<<2);
      float bv = 0.f;
      if (FLAGS & GF_BIAS) bv = bias[col];
      #pragma unroll
      for (int q=0;q<4;++q){
        const int row = row0 + q;
        float xv = acc[mi][ni][q] + bv;
        if (FLAGS & GF_ADDY) xv += addy[(size_t)(row&255)*lday + col];
        if (FLAGS & GF_TANH) xv = tanh_fast(xv);
        if (FLAGS & GF_CHK){
          if (col < H_){
            const float u = xv + b2f(chkbase[(size_t)row*H_ + col]);
            chkhid[(size_t)row*H_ + col] = f2b(tanh_fast(u));
          } else if (col == H_){
            Cf[row] = xv;   // logits
          }
        } else {
          if (FLAGS & GF_WF32)  Cf[zc + (size_t)row*ldC + col] = xv;
          if (FLAGS & GF_WBF16) Cb[zc + (size_t)row*ldC + col] = f2b(xv);
        }
      }
    }
  }
}

// ---------------- persistent bi-GRU encoder (fence-free sc1 exchange) ----------------
__global__ __launch_bounds__(256,1)
void enc_persist(const float* __restrict__ Wf, const float* __restrict__ Wb,
                 const float* __restrict__ bhf, const float* __restrict__ bhb,
                 const ushort* __restrict__ gif, const ushort* __restrict__ gib,
                 ushort* __restrict__ hG, uint* __restrict__ flags,
                 ushort* __restrict__ encout, ushort* __restrict__ encoutT,
                 float* __restrict__ hTf, float* __restrict__ hTb)
{
  const int g = blockIdx.x;
  const int dir = g >> 5;
  const int j0 = (g & 31) << 4;
  const int tid = threadIdx.x;
  const int w = tid >> 6, lane = tid & 63;
  const int mi = w & 1, kh = w >> 1;
  const int l15 = lane & 15, l4 = lane >> 4;
  const int brow0 = mi*16 + l4*4;

  const float* W = dir ? Wb : Wf;
  const float* bh = dir ? bhb : bhf;
  const ushort* gi = dir ? gib : gif;

  __shared__ __align__(16) float cred[2][3][256];
  __shared__ float bhl[48];

  // weight slice in registers: 3 gates x 8 k-steps (bf16 B-fragments)
  short8 bw[3][8];
  {
    const int kbase = kh*256 + l4*8;
    #pragma unroll
    for (int ni=0; ni<3; ++ni){
      const float* wr = W + (size_t)(ni*512 + j0 + l15)*512 + kbase;
      #pragma unroll
      for (int ks=0; ks<8; ++ks){
        const float4 f0 = *(const float4*)(wr + ks*32);
        const float4 f1 = *(const float4*)(wr + ks*32 + 4);
        short8 v;
        v[0]=(short)f2b(f0.x); v[1]=(short)f2b(f0.y); v[2]=(short)f2b(f0.z); v[3]=(short)f2b(f0.w);
        v[4]=(short)f2b(f1.x); v[5]=(short)f2b(f1.y); v[6]=(short)f2b(f1.z); v[7]=(short)f2b(f1.w);
        bw[ni][ks] = v;
      }
    }
  }
  if (tid < 48) bhl[tid] = bh[(tid>>4)*512 + j0 + (tid&15)];
  __syncthreads();

  float bh0r=0.f, bh1r=0.f, bh2r=0.f;
  if (kh==0){ bh0r = bhl[l15]; bh1r = bhl[16+l15]; bh2r = bhl[32+l15]; }
  float holdr[4] = {0.f,0.f,0.f,0.f};
  uint* myflag = flags + dir*32 + (g&31);

  for (int t=0; t<128; ++t){
    const int tt = dir ? (127 - t) : t;
    if (t){
      if (tid < 32){
        const uint* fp = flags + dir*32 + tid;
        while (ld_flag(fp) < (uint)t) __builtin_amdgcn_s_sleep(2);
      }
      __syncthreads();
    }
    // A-fragments straight from the coherent exchange buffer
    const ushort* hsrc = hG + ((size_t)((t&1)*2 + dir))*32768 + (size_t)(mi*16+l15)*1024 + kh*256 + l4*8;
    u32x4 a0,a1,a2,a3,a4,a5,a6,a7,b0,b1,b2,b3,b4,b5,b6,b7;
    asm volatile(
      "global_load_dwordx4 %0, %16, off sc0 sc1\n\t"
      "global_load_dwordx4 %1, %16, off offset:64 sc0 sc1\n\t"
      "global_load_dwordx4 %2, %16, off offset:128 sc0 sc1\n\t"
      "global_load_dwordx4 %3, %16, off offset:192 sc0 sc1\n\t"
      "global_load_dwordx4 %4, %16, off offset:256 sc0 sc1\n\t"
      "global_load_dwordx4 %5, %16, off offset:320 sc0 sc1\n\t"
      "global_load_dwordx4 %6, %16, off offset:384 sc0 sc1\n\t"
      "global_load_dwordx4 %7, %16, off offset:448 sc0 sc1\n\t"
      "global_load_dwordx4 %8, %16, off offset:1024 sc0 sc1\n\t"
      "global_load_dwordx4 %9, %16, off offset:1088 sc0 sc1\n\t"
      "global_load_dwordx4 %10, %16, off offset:1152 sc0 sc1\n\t"
      "global_load_dwordx4 %11, %16, off offset:1216 sc0 sc1\n\t"
      "global_load_dwordx4 %12, %16, off offset:1280 sc0 sc1\n\t"
      "global_load_dwordx4 %13, %16, off offset:1344 sc0 sc1\n\t"
      "global_load_dwordx4 %14, %16, off offset:1408 sc0 sc1\n\t"
      "global_load_dwordx4 %15, %16, off offset:1472 sc0 sc1\n\t"
      "s_waitcnt vmcnt(0)"
      : "=&v"(a0),"=&v"(a1),"=&v"(a2),"=&v"(a3),"=&v"(a4),"=&v"(a5),"=&v"(a6),"=&v"(a7),
        "=&v"(b0),"=&v"(b1),"=&v"(b2),"=&v"(b3),"=&v"(b4),"=&v"(b5),"=&v"(b6),"=&v"(b7)
      : "v"(hsrc)
      : "memory");
    const short8 ah[8] = {cvt8(a0),cvt8(a1),cvt8(a2),cvt8(a3),cvt8(a4),cvt8(a5),cvt8(a6),cvt8(a7)};
    const short8 al[8] = {cvt8(b0),cvt8(b1),cvt8(b2),cvt8(b3),cvt8(b4),cvt8(b5),cvt8(b6),cvt8(b7)};
    f32x4 acc[3]; acc[0]=0.f; acc[1]=0.f; acc[2]=0.f;
    #pragma unroll
    for (int ks=0; ks<8; ++ks){
      acc[0] = __builtin_amdgcn_mfma_f32_16x16x32_bf16(ah[ks], bw[0][ks], acc[0],0,0,0);
      acc[1] = __builtin_amdgcn_mfma_f32_16x16x32_bf16(ah[ks], bw[1][ks], acc[1],0,0,0);
      acc[2] = __builtin_amdgcn_mfma_f32_16x16x32_bf16(ah[ks], bw[2][ks], acc[2],0,0,0);
      acc[0] = __builtin_amdgcn_mfma_f32_16x16x32_bf16(al[ks], bw[0][ks], acc[0],0,0,0);
      acc[1] = __builtin_amdgcn_mfma_f32_16x16x32_bf16(al[ks], bw[1][ks], acc[1],0,0,0);
      acc[2] = __builtin_amdgcn_mfma_f32_16x16x32_bf16(al[ks], bw[2][ks], acc[2],0,0,0);
    }
    if (kh==1){
      #pragma unroll
      for (int ni=0; ni<3; ++ni) *(f32x4*)&cred[mi][ni][lane*4] = acc[ni];
    }
    __syncthreads();
    if (kh==0){
      #pragma unroll
      for (int ni=0; ni<3; ++ni){
        const f32x4 o = *(const f32x4*)&cred[mi][ni][lane*4];
        acc[ni][0]+=o[0]; acc[ni][1]+=o[1]; acc[ni][2]+=o[2]; acc[ni][3]+=o[3];
      }
      ushort* dst = hG + ((size_t)(((t+1)&1)*2 + dir))*32768;
      const ushort* girow = gi + ((size_t)tt*32 + brow0)*1536 + j0 + l15;
      #pragma unroll
      for (int q=0; q<4; ++q){
        const int b = brow0 + q;
        const float gi0 = b2f(girow[q*1536]);
        const float gi1 = b2f(girow[q*1536 + 512]);
        const float gi2 = b2f(girow[q*1536 + 1024]);
        const float r  = sigf(gi0 + acc[0][q] + bh0r);
        const float zg = sigf(gi1 + acc[1][q] + bh1r);
        const float n  = tanh_fast(gi2 + r*(acc[2][q] + bh2r));
        const float h2 = (1.f - zg)*n + zg*holdr[q];
        holdr[q] = h2;
        const ushort hb = f2b(h2);
        const ushort hl = f2b(h2 - b2f(hb));
        if (t < 127){
          st_h16(dst + (size_t)b*1024 + j0 + l15, (uint)hb);
          st_h16(dst + (size_t)b*1024 + 512 + j0 + l15, (uint)hl);
        }
        encout[((size_t)b*SIN_ + tt)*1024 + dir*H_ + j0 + l15] = hb;
        encoutT[((size_t)b*1024 + dir*H_ + j0 + l15)*SIN_ + tt] = hb;
      }
    }
    __syncthreads();   // drains all waves' vmcnt (incl. sc1 stores) before flag
    if (t < 127 && tid == 0) st_flag(myflag, (uint)(t+1));
  }
  if (kh==0){
    float* hT = dir ? hTb : hTf;
    #pragma unroll
    for (int q=0; q<4; ++q) hT[(size_t)(brow0+q)*H_ + j0 + l15] = holdr[q];
  }
}

// embsum = bf16(emb + trans)
__global__ void k_embsum(const ushort* __restrict__ embxs, const float* __restrict__ transo,
                         ushort* __restrict__ esum)
{
  for (long i = (long)blockIdx.x*blockDim.x + threadIdx.x; i < (long)B_*SIN_*E_; i += (long)gridDim.x*blockDim.x){
    int e = (int)(i & 255); long bs = i >> 8; int s = (int)(bs & 127); int bb = (int)(bs >> 7);
    esum[i] = f2b(b2f(embxs[((size_t)s*B_ + bb)*E_ + e]) + transo[i]);
  }
}

// row softmax over SIN=128, one wave per row
__global__ __launch_bounds__(256) void k_softmax(const float* __restrict__ sc, ushort* __restrict__ al)
{
  const int row = blockIdx.x*4 + (threadIdx.x>>6);
  const int lane = threadIdx.x&63;
  const float* s = sc + (size_t)row*SIN_;
  const float2 v = *(const float2*)&s[lane*2];
  float m = fmaxf(v.x, v.y);
  #pragma unroll
  for (int o=1;o<64;o<<=1) m = fmaxf(m, __shfl_xor(m, o));
  const float e0 = __expf(v.x - m), e1 = __expf(v.y - m);
  float sum = e0 + e1;
  #pragma unroll
  for (int o=1;o<64;o<<=1) sum += __shfl_xor(sum, o);
  const float inv = 1.f/sum;
  ushort* a = al + (size_t)row*SIN_;
  const uint pkv = (uint)f2b(e0*inv) | ((uint)f2b(e1*inv)<<16);
  *(uint*)&a[lane*2] = pkv;
}

// h0_dec = tanh(hidden_cat @ merge_W^T + merge_b), with the reference's odd reshape
__global__ __launch_bounds__(512)
void k_merge(const float* __restrict__ hTf, const float* __restrict__ hTb,
             const float* __restrict__ mW, const float* __restrict__ mb,
             float* __restrict__ h0)
{
  const int b = blockIdx.x, j = threadIdx.x;
  __shared__ float hc[1024];
  for (int i=j; i<1024; i+=512){
    const int half = i >> 9, jj = i & 511;
    hc[i] = (b < 16) ? hTf[(size_t)(2*b + half)*H_ + jj] : hTb[(size_t)(2*(b-16) + half)*H_ + jj];
  }
  __syncthreads();
  float d = mb[j];
  const float* wr = mW + (size_t)j*1024;
  #pragma unroll 8
  for (int k=0;k<1024;k+=4){
    const float4 a = *(const float4*)&wr[k];
    const float4 hh = *(const float4*)&hc[k];
    d += a.x*hh.x + a.y*hh.y + a.z*hh.z + a.w*hh.w;
  }
  h0[(size_t)b*H_ + j] = tanh_fast(d);
}

__global__ void k_bcast(const float* __restrict__ h0, float* __restrict__ hf, ushort* __restrict__ hb)
{
  for (long i = (long)blockIdx.x*blockDim.x + threadIdx.x; i < (long)8192*H_; i += (long)gridDim.x*blockDim.x){
    const int jj = (int)(i & 511); const long row = i >> 9; const int bb = (int)(row >> 8);
    const float v = h0[(size_t)bb*H_ + jj];
    hf[i] = v; hb[i] = f2b(v);
  }
}

// ---------------- fused decoder recurrent GEMM + gates ----------------
// grid (4, 64): bx = 128-j block, by = 128-row block. 512 threads = 8 waves (2 row x 4 col).
__global__ __launch_bounds__(512,1)
void gemm_dec(const ushort* __restrict__ A, const ushort* __restrict__ Wd,
              const ushort* __restrict__ gib, const float* __restrict__ sproj_t,
              const float* __restrict__ wchk, const float* __restrict__ dbhh,
              const float* __restrict__ checked, int t,
              const float* __restrict__ hin, float* __restrict__ hout,
              ushort* __restrict__ h2bo)
{
  const int bx = blockIdx.x;
  const int by = blockIdx.y;
  const int bm = by<<7;
  const int tid = threadIdx.x;
  const int w = tid>>6, lane = tid&63;
  const int wrh = w>>2, wc = w&3;
  const int wm = wrh<<6;
  const int l15 = lane&15, l4 = lane>>4;
  __shared__ ushort lsA[128*72];
  __shared__ ushort lsB[384*72];
  f32x4 acc[3][4][2];
  #pragma unroll
  for (int gg=0;gg<3;++gg)
    #pragma unroll
    for (int mi2=0;mi2<4;++mi2)
      #pragma unroll
      for (int ni2=0;ni2<2;++ni2) acc[gg][mi2][ni2] = 0.f;

  // staging slot geometry
  const int saRow0 = tid>>3, saK = (tid&7)<<3;        // A: slot tid (+512): rows 0..63 / 64..127
  uint4 va[2], vb[6];
  {
    #pragma unroll
    for (int i=0;i<2;++i){
      const int row = saRow0 + (i<<6);
      va[i] = *(const uint4*)&A[(size_t)(bm+row)*512 + saK];
    }
    #pragma unroll
    for (int i=0;i<6;++i){
      const int s = tid + (i<<9);
      const int gg = s>>10, w1 = s&1023, row = w1>>3, kc = (w1&7)<<3;
      vb[i] = *(const uint4*)&Wd[(size_t)((gg<<9) + (bx<<7) + row)*512 + kc];
    }
  }
  for (int kt=0; kt<8; ++kt){
    __syncthreads();
    #pragma unroll
    for (int i=0;i<2;++i){
      const int row = saRow0 + (i<<6);
      *(uint4*)&lsA[row*72 + saK] = va[i];
    }
    #pragma unroll
    for (int i=0;i<6;++i){
      const int s = tid + (i<<9);
      const int gg = s>>10, w1 = s&1023, row = w1>>3, kc = (w1&7)<<3;
      *(uint4*)&lsB[((gg<<7)+row)*72 + kc] = vb[i];
    }
    __syncthreads();
    if (kt < 7){
      const int ko = (kt+1)<<6;
      #pragma unroll
      for (int i=0;i<2;++i){
        const int row = saRow0 + (i<<6);
        va[i] = *(const uint4*)&A[(size_t)(bm+row)*512 + ko + saK];
      }
      #pragma unroll
      for (int i=0;i<6;++i){
        const int s = tid + (i<<9);
        const int gg = s>>10, w1 = s&1023, row = w1>>3, kc = (w1&7)<<3;
        vb[i] = *(const uint4*)&Wd[(size_t)((gg<<9) + (bx<<7) + row)*512 + ko + kc];
      }
    }
    #pragma unroll
    for (int ks=0;ks<2;++ks){
      short8 af[4];
      #pragma unroll
      for (int mi2=0;mi2<4;++mi2)
        af[mi2] = *(const short8*)&lsA[(wm + (mi2<<4) + l15)*72 + (ks<<5) + (l4<<3)];
      short8 bf[3][2];
      #pragma unroll
      for (int gg=0;gg<3;++gg)
        #pragma unroll
        for (int ni2=0;ni2<2;++ni2)
          bf[gg][ni2] = *(const short8*)&lsB[((gg<<7) + (wc<<5) + (ni2<<4) + l15)*72 + (ks<<5) + (l4<<3)];
      #pragma unroll
      for (int gg=0;gg<3;++gg)
        #pragma unroll
        for (int mi2=0;mi2<4;++mi2)
          #pragma unroll
          for (int ni2=0;ni2<2;++ni2)
            acc[gg][mi2][ni2] = __builtin_amdgcn_mfma_f32_16x16x32_bf16(af[mi2], bf[gg][ni2], acc[gg][mi2][ni2], 0,0,0);
    }
  }
  // epilogue: gates
  const int bb = by>>1;
  const float* sp = sproj_t + (size_t)bb*TH_;
  const int jbase = (bx<<7) + (wc<<5);
  float spv[3][2], wcv[3][2], bhnv[2];
  #pragma unroll
  for (int ni2=0;ni2<2;++ni2){
    const int j = jbase + (ni2<<4) + l15;
    spv[0][ni2] = sp[j]; spv[1][ni2] = sp[512+j]; spv[2][ni2] = sp[1024+j];
    wcv[0][ni2] = wchk[j]; wcv[1][ni2] = wchk[512+j]; wcv[2][ni2] = wchk[1024+j];
    bhnv[ni2] = dbhh[1024+j];
  }
  const float* ckrow = checked + ((size_t)(bb*33 + t))*Y_;
  #pragma unroll
  for (int mi2=0;mi2<4;++mi2){
    #pragma unroll
    for (int q=0;q<4;++q){
      const int row = bm + wm + (mi2<<4) + (l4<<2) + q;
      const float ck = ckrow[row & 255];
      #pragma unroll
      for (int ni2=0;ni2<2;++ni2){
        const int j = jbase + (ni2<<4) + l15;
        const float g0 = b2f(gib[(size_t)row*TH_ + j]);
        const float g1 = b2f(gib[(size_t)row*TH_ + 512 + j]);
        const float g2 = b2f(gib[(size_t)row*TH_ + 1024 + j]);
        const float hold = hin[(size_t)row*H_ + j];
        const float r  = sigf(g0 + spv[0][ni2] + ck*wcv[0][ni2] + acc[0][mi2][ni2][q]);
        const float zg = sigf(g1 + spv[1][ni2] + ck*wcv[1][ni2] + acc[1][mi2][ni2][q]);
        const float n  = tanh_fast(g2 + spv[2][ni2] + ck*wcv[2][ni2] + r*(acc[2][mi2][ni2][q] + bhnv[ni2]));
        const float h2 = (1.f - zg)*n + zg*hold;
        hout[(size_t)row*H_ + j] = h2;
        h2bo[(size_t)row*H_ + j] = f2b(h2);
      }
    }
  }
}

// ---------------- per-step losses ----------------
__global__ __launch_bounds__(256)
void dec_loss(const ushort* __restrict__ chkhid, const float* __restrict__ cw2,
              const float* __restrict__ cb2v, const float* __restrict__ checked,
              const float* __restrict__ yv, const float* __restrict__ logits,
              int t, float* __restrict__ acc)
{
  const int tid = threadIdx.x;
  if (blockIdx.x < 64){
    const int wv = tid>>6, lane = tid&63;
    const float4 w20 = *(const float4*)&cw2[lane*8];
    const float4 w21 = *(const float4*)&cw2[lane*8+4];
    const float w2a[8] = {w20.x,w20.y,w20.z,w20.w,w21.x,w21.y,w21.z,w21.w};
    const float bb2 = cb2v[0];
    float wsum = 0.f;
    for (int i=0;i<32;++i){
      const int row = blockIdx.x*128 + wv*32 + i;
      const uint4 hv = *(const uint4*)&chkhid[(size_t)row*H_ + lane*8];
      const ushort* ph = (const ushort*)&hv;
      float p = 0.f;
      #pragma unroll
      for (int e=0;e<8;++e) p += b2f(ph[e]) * w2a[e];
      #pragma unroll
      for (int o=1;o<64;o<<=1) p += __shfl_xor(p, o);
      if (lane==0){
        const int bb = row>>8, yy = row&255;
        const float u = p + bb2;
        const float c = checked[((size_t)bb*33 + (t+1))*Y_ + yy];
        const float yt = yv[((size_t)bb*SOUT_ + t)*Y_ + yy];
        wsum += yt * (c*splus(-u) + (1.f-c)*splus(u));
      }
    }
    if (lane==0) atomicAdd(acc+1, wsum);
  } else {
    __shared__ float red[256];
    __shared__ float bmx[32], bsm[32];
    const int bb = tid>>3, part = tid&7;
    float lv[32];
    const float* lg = logits + bb*Y_ + part*32;
    float m = -1e30f;
    #pragma unroll
    for (int i=0;i<32;++i){ lv[i] = lg[i]; m = fmaxf(m, lv[i]); }
    red[tid] = m; __syncthreads();
    if (part==0){ float mm = red[tid];
      #pragma unroll
      for (int k2=1;k2<8;++k2) mm = fmaxf(mm, red[tid+k2]);
      bmx[bb] = mm; }
    __syncthreads();
    const float bm = bmx[bb];
    float se = 0.f;
    #pragma unroll
    for (int i=0;i<32;++i) se += __expf(lv[i]-bm);
    red[tid] = se; __syncthreads();
    if (part==0){ float ss = 0.f;
      #pragma unroll
      for (int k2=0;k2<8;++k2) ss += red[tid+k2];
      bsm[bb] = ss; }
    __syncthreads();
    const float lse = bm + logf(bsm[bb]);
    const float* yr = yv + ((size_t)bb*SOUT_ + t)*Y_ + part*32;
    float pl = 0.f;
    #pragma unroll
    for (int i=0;i<32;++i) pl += yr[i]*(lv[i]-lse);
    red[tid] = pl; __syncthreads();
    if (tid==0){ float s = 0.f;
      for (int k2=0;k2<256;++k2) s += red[k2];
      atomicAdd(acc+0, -s); }
  }
}

__global__ void k_final(const float* __restrict__ acc, float* __restrict__ out)
{
  if (threadIdx.x==0){
    const float ls = acc[0], cls = acc[1], ys = acc[2];
    out[0] = (ls+cls)/ys; out[1] = ls/ys; out[2] = cls/ys;
  }
}

// ---------------- host ----------------
extern "C" void kernel_launch(void* const* d_in, const int* in_sizes, int n_in,
                              void* d_out, int out_size, void* d_ws, size_t ws_size,
                              hipStream_t stream)
{
  (void)in_sizes; (void)n_in; (void)out_size;
  const int*   x      = (const int*)d_in[0];
  const int*   akey   = (const int*)d_in[1];
  const int*   atype  = (const int*)d_in[2];
  const int*   croom  = (const int*)d_in[3];
  const float* checked= (const float*)d_in[4];
  const float* yv     = (const float*)d_in[5];
  const float* emb    = (const float*)d_in[6];
  const float* attab  = (const float*)d_in[7];
  const float* eWihF  = (const float*)d_in[8];
  const float* eWhhF  = (const float*)d_in[9];
  const float* ebihF  = (const float*)d_in[10];
  const float* ebhhF  = (const float*)d_in[11];
  const float* eWihB  = (const float*)d_in[12];
  const float* eWhhB  = (const float*)d_in[13];
  const float* ebihB  = (const float*)d_in[14];
  const float* ebhhB  = (const float*)d_in[15];
  const float* transW = (const float*)d_in[16];
  const float* transb = (const float*)d_in[17];
  const float* mergeW = (const float*)d_in[18];
  const float* mergeb = (const float*)d_in[19];
  const float* dWih   = (const float*)d_in[20];
  const float* dWhh   = (const float*)d_in[21];
  const float* dbih   = (const float*)d_in[22];
  const float* dbhh   = (const float*)d_in[23];
  const float* dW     = (const float*)d_in[24];
  const float* cW1    = (const float*)d_in[26];
  const float* cb1    = (const float*)d_in[27];
  const float* cW2    = (const float*)d_in[28];
  const float* cb2    = (const float*)d_in[29];

  char* base = (char*)d_ws;
  size_t off = 0;
  auto alloc = [&](size_t bytes)->char*{ char* p = base + off; off += (bytes + 255) & ~(size_t)255; return p; };

  float*  accv   = (float*)alloc(256);
  ushort* embxs  = (ushort*)alloc((size_t)SIN_*B_*E_*2);
  ushort* aemb   = (ushort*)alloc((size_t)Y_*E_*2);
  ushort* aembT  = (ushort*)alloc((size_t)Y_*E_*2);
  float*  avec   = (float*)alloc((size_t)Y_*32*4);
  ushort* yprev  = (ushort*)alloc((size_t)SOUT_*B_*Y_*2);
  ushort* acat   = (ushort*)alloc((size_t)SOUT_*B_*512*2);
  ushort* gi_fb  = (ushort*)alloc((size_t)2*SIN_*B_*TH_*2);   // gi_f | gi_b ; later aliased by gi_base
  ushort* gi_f   = gi_fb;
  ushort* gi_b   = gi_fb + (size_t)SIN_*B_*TH_;
  ushort* gibase = gi_fb;
  ushort* encout = (ushort*)alloc((size_t)B_*SIN_*1024*2);    // + encoutT region reused as hbuf0
  ushort* encoutT= (ushort*)alloc((size_t)B_*1024*SIN_*2);
  float*  hbuf0  = (float*)encout;                            // 8192*512*4 == encout+encoutT exactly
  float*  hTf    = (float*)alloc((size_t)B_*H_*4);
  float*  hTb    = (float*)alloc((size_t)B_*H_*4);
  float*  h0dec  = (float*)alloc((size_t)B_*H_*4);
  float*  transo = (float*)alloc((size_t)B_*SIN_*E_*4);
  ushort* esum   = (ushort*)alloc((size_t)B_*SIN_*E_*2);
  float*  scores = (float*)alloc((size_t)B_*Y_*SIN_*4);
  ushort* alpha  = (ushort*)alloc((size_t)B_*Y_*SIN_*2);
  ushort* att    = (ushort*)alloc((size_t)8192*1024*2);
  ushort* chkbase= (ushort*)alloc((size_t)8192*H_*2);
  float*  addy   = (float*)alloc((size_t)Y_*TH_*4);
  float*  addcy  = (float*)alloc((size_t)Y_*H_*4);
  float*  sproj  = (float*)alloc((size_t)SOUT_*B_*TH_*4);
  float*  wchk   = (float*)alloc((size_t)TH_*4);
  float*  dbhhrz = (float*)alloc((size_t)TH_*4);
  ushort* WihFb  = (ushort*)alloc((size_t)TH_*E_*2);
  ushort* WihBb  = (ushort*)alloc((size_t)TH_*E_*2);
  ushort* Wtrb   = (ushort*)alloc((size_t)E_*1024*2);
  ushort* Wattb  = (ushort*)alloc((size_t)TH_*1024*2);
  ushort* Wcat2b = (ushort*)alloc((size_t)TH_*512*2);
  ushort* W1attb = (ushort*)alloc((size_t)H_*1024*2);
  ushort* Wdecb  = (ushort*)alloc((size_t)TH_*512*2);
  ushort* Wchk2b = (ushort*)alloc((size_t)640*512*2);
  float*  hbuf1  = (float*)alloc((size_t)8192*H_*4);
  ushort* h2bA   = (ushort*)alloc((size_t)8192*H_*2);
  ushort* h2bB   = (ushort*)alloc((size_t)8192*H_*2);
  ushort* chkhid = (ushort*)alloc((size_t)8192*H_*2);
  float*  logits = (float*)alloc((size_t)8192*4);
  ushort* hG     = (ushort*)alloc((size_t)2*2*32*1024*2);     // h exchange: [buf][dir][b][hi512|lo512]
  uint*   flags  = (uint*)alloc((size_t)256*4);

  if (off > ws_size){ k_wsfail<<<1,1,0,stream>>>((float*)d_out); return; }

  float* outp = (float*)d_out;

  k_init<<<dim3(1), dim3(64), 0, stream>>>(accv);
  k_init_enc<<<dim3(64), dim3(256), 0, stream>>>(flags, hG);
  k_ysum<<<dim3(256), dim3(256), 0, stream>>>(yv, accv);
  k_lookup<<<dim3(2048), dim3(256), 0, stream>>>(x, akey, atype, croom, yv, emb, attab,
                                                 embxs, aemb, aembT, avec, acat, yprev);
  auto conv = [&](const float* s, ushort* d, int r, int c, int sld, int dld, int doff){
    k_conv<<<dim3(512), dim3(256), 0, stream>>>(s, d, r, c, sld, dld, doff);
  };
  conv(eWihF, WihFb, TH_, E_, E_, E_, 0);
  conv(eWihB, WihBb, TH_, E_, E_, E_, 0);
  conv(transW, Wtrb, E_, 1024, 1024, 1024, 0);
  conv(dWih, Wattb, TH_, 1024, 1569, 1024, 0);
  conv(dWih+1025, Wcat2b, TH_, 256, 1569, 512, 0);
  conv(dWih+1313, Wcat2b, TH_, 256, 1569, 512, 256);
  conv(cW1, W1attb, H_, 1024, 1568, 1024, 0);
  conv(dWhh, Wdecb, TH_, 512, 512, 512, 0);
  conv(cW1+1056, Wchk2b, H_, 512, 1568, 512, 0);
  conv(dW, Wchk2b + (size_t)512*512, 1, 512, 512, 512, 0);
  k_prep2<<<dim3(1024), dim3(256), 0, stream>>>(avec, dWih, dbih, cW1, cb1, dbhh,
                                                addy, addcy, wchk, dbhhrz);

  // encoder input projections (bias folded in)
  gemm_nt<(GF_BIAS|GF_WBF16)><<<dim3(12,32,1), dim3(256), 0, stream>>>(
    embxs, WihFb, ebihF, nullptr, 0, nullptr, gi_f, TH_, E_, E_, E_, 0, 0L,0L,0L, nullptr, nullptr);
  gemm_nt<(GF_BIAS|GF_WBF16)><<<dim3(12,32,1), dim3(256), 0, stream>>>(
    embxs, WihBb, ebihB, nullptr, 0, nullptr, gi_b, TH_, E_, E_, E_, 0, 0L,0L,0L, nullptr, nullptr);

  enc_persist<<<dim3(64), dim3(256), 0, stream>>>(eWhhF, eWhhB, ebhhF, ebhhB, gi_f, gi_b,
                                                  hG, flags, encout, encoutT, hTf, hTb);

  // trans_out = tanh(enc_out @ trans_W^T + b)
  gemm_nt<(GF_BIAS|GF_TANH|GF_WF32)><<<dim3(2,32,1), dim3(256), 0, stream>>>(
    encout, Wtrb, transb, nullptr, 0, transo, nullptr, E_, 1024, 1024, 1024, 0, 0L,0L,0L, nullptr, nullptr);
  k_embsum<<<dim3(1024), dim3(256), 0, stream>>>(embxs, transo, esum);

  // scores[b] = action_emb @ embsum_b^T  (batched over b)
  gemm_nt<GF_WF32><<<dim3(1,2,32), dim3(256), 0, stream>>>(
    aemb, esum, nullptr, nullptr, 0, scores, nullptr, SIN_, E_, E_, E_, 0,
    0L, (long)SIN_*E_, (long)Y_*SIN_, nullptr, nullptr);
  k_softmax<<<dim3(2048), dim3(256), 0, stream>>>(scores, alpha);

  // attention[b] = alpha_b @ enc_out_b   (W = enc_outT_b)
  gemm_nt<GF_WBF16><<<dim3(8,2,32), dim3(256), 0, stream>>>(
    alpha, encoutT, nullptr, nullptr, 0, nullptr, att, 1024, SIN_, SIN_, SIN_, 0,
    (long)Y_*SIN_, (long)1024*SIN_, (long)Y_*1024, nullptr, nullptr);

  k_merge<<<dim3(32), dim3(512), 0, stream>>>(hTf, hTb, mergeW, mergeb, h0dec);

  // yemb -> acat[:,256:512]
  gemm_nt<GF_WBF16><<<dim3(2,8,1), dim3(256), 0, stream>>>(
    yprev, aembT, nullptr, nullptr, 0, nullptr, acat+256, 512, Y_, Y_, Y_, 0, 0L,0L,0L, nullptr, nullptr);
  // sproj = acat @ Wcat2^T + dbhh_rz  (room + y parts of dec_Wih, all 32 steps; r/z bhh folded)
  gemm_nt<(GF_BIAS|GF_WF32)><<<dim3(12,8,1), dim3(256), 0, stream>>>(
    acat, Wcat2b, dbhhrz, nullptr, 0, sproj, nullptr, TH_, 512, 512, 512, 0, 0L,0L,0L, nullptr, nullptr);

  // gi_base = att @ W_att^T + add_y[y]   ;  chk_base = att @ W1_att^T + addc_y[y]
  gemm_nt<(GF_WBF16|GF_ADDY)><<<dim3(12,64,1), dim3(256), 0, stream>>>(
    att, Wattb, nullptr, addy, TH_, nullptr, gibase, TH_, 1024, 1024, 1024, 0, 0L,0L,0L, nullptr, nullptr);
  gemm_nt<(GF_WBF16|GF_ADDY)><<<dim3(4,64,1), dim3(256), 0, stream>>>(
    att, W1attb, nullptr, addcy, H_, nullptr, chkbase, H_, 1024, 1024, 1024, 0, 0L,0L,0L, nullptr, nullptr);

  k_bcast<<<dim3(4096), dim3(256), 0, stream>>>(h0dec, hbuf0, h2bA);

  for (int t=0; t<SOUT_; ++t){
    ushort* hin_b  = (t&1) ? h2bB : h2bA;
    ushort* hout_b = (t&1) ? h2bA : h2bB;
    float*  hinf   = (t&1) ? hbuf1 : hbuf0;
    float*  houtf  = (t&1) ? hbuf0 : hbuf1;
    gemm_dec<<<dim3(4,64), dim3(512), 0, stream>>>(
      hin_b, Wdecb, gibase, sproj + (size_t)t*B_*TH_, wchk, dbhh, checked, t,
      hinf, houtf, hout_b);
    gemm_nt<GF_CHK><<<dim3(5,64), dim3(256), 0, stream>>>(
      hout_b, Wchk2b, nullptr, nullptr, 0, logits, nullptr, 0, 512, 512, 512, 0,
      0L,0L,0L, chkbase, chkhid);
    dec_loss<<<dim3(65), dim3(256), 0, stream>>>(chkhid, cW2, cb2, checked, yv, logits, t, accv);
  }
  k_final<<<dim3(1), dim3(1), 0, stream>>>(accv, outp);
}

// Round 4
// 4077.006 us; speedup vs baseline: 4.5534x; 1.4485x over previous
//
#include <hip/hip_runtime.h>

typedef unsigned short ushort;
typedef unsigned int uint;
typedef __attribute__((ext_vector_type(8))) short short8;
typedef __attribute__((ext_vector_type(4))) float f32x4;
typedef __attribute__((ext_vector_type(4))) uint u32x4;

#define DEVI __device__ __forceinline__

#define B_ 32
#define SIN_ 128
#define SOUT_ 32
#define Y_ 256
#define H_ 512
#define E_ 256
#define TH_ 1536

DEVI float b2f(ushort u){ return __uint_as_float(((uint)u)<<16); }
DEVI ushort f2b(float f){ uint x = __float_as_uint(f); return (ushort)((x + 0x7FFFu + ((x>>16)&1u)) >> 16); }
DEVI float sigf(float x){ return 1.f/(1.f+__expf(-x)); }
DEVI float tanh_fast(float x){ return 2.f/(1.f+__expf(-2.f*x)) - 1.f; }
DEVI float splus(float x){ return fmaxf(x,0.f) + log1pf(__expf(-fabsf(x))); }
DEVI short8 cvt8(u32x4 v){ return __builtin_bit_cast(short8, v); }

// sc0 sc1 = coherent through Infinity Cache (cross-XCD visible without fences)
DEVI uint ld_flag(const uint* p){
  uint r;
  asm volatile("global_load_dword %0, %1, off sc0 sc1\n\ts_waitcnt vmcnt(0)"
               : "=v"(r) : "v"(p) : "memory");
  return r;
}
DEVI void st_flag(uint* p, uint v){
  asm volatile("global_store_dword %0, %1, off sc0 sc1" :: "v"(p), "v"(v) : "memory");
}
DEVI void st_h16(ushort* p, uint v){
  asm volatile("global_store_short %0, %1, off sc0 sc1" :: "v"(p), "v"(v) : "memory");
}

// ---------------- init / reductions ----------------
__global__ void k_init(float* acc){ if (threadIdx.x < 4) acc[threadIdx.x] = 0.f; }

__global__ void k_wsfail(float* out){ out[0]=1.2345e8f; out[1]=2.3456e8f; out[2]=3.4567e8f; }

__global__ void k_init_enc(uint* __restrict__ flags, ushort* __restrict__ hG)
{
  const int id = blockIdx.x*256 + threadIdx.x;
  if (id < 256) flags[id] = 0u;
  if (id < 16384) ((uint4*)hG)[id] = make_uint4(0,0,0,0);
}

__global__ __launch_bounds__(256) void k_ysum(const float* __restrict__ yv, float* __restrict__ acc)
{
  __shared__ float red[256];
  float s = 0.f;
  for (long i = (long)blockIdx.x*256 + threadIdx.x; i < (long)B_*SOUT_*Y_; i += (long)gridDim.x*256) s += yv[i];
  red[threadIdx.x] = s; __syncthreads();
  for (int o=128;o;o>>=1){ if ((int)threadIdx.x<o) red[threadIdx.x] += red[threadIdx.x+o]; __syncthreads(); }
  if (threadIdx.x==0) atomicAdd(acc+2, red[0]);
}

// ---------------- embedding / lookup ----------------
__global__ void k_lookup(const int* __restrict__ x, const int* __restrict__ akey,
                         const int* __restrict__ atype, const int* __restrict__ croom,
                         const float* __restrict__ yv,
                         const float* __restrict__ emb, const float* __restrict__ attab,
                         ushort* __restrict__ embxs, ushort* __restrict__ aemb,
                         ushort* __restrict__ aembT, float* __restrict__ avec,
                         ushort* __restrict__ acat, ushort* __restrict__ yprev)
{
  const long N1 = (long)SIN_*B_*E_;
  const long N2 = (long)Y_*E_;
  const long N3 = (long)Y_*32;
  const long N4 = (long)SOUT_*B_*E_;
  const long N5 = (long)SOUT_*B_*Y_;
  for (long i = (long)blockIdx.x*blockDim.x + threadIdx.x; i < N1+N2+N3+N4+N5; i += (long)gridDim.x*blockDim.x){
    long id = i;
    if (id < N1){
      int e = id & 255; long sb = id >> 8; int bb = (int)(sb & 31); int s = (int)(sb >> 5);
      embxs[id] = f2b(emb[(size_t)x[bb*SIN_ + s]*E_ + e]);
    } else if ((id -= N1) < N2){
      int e = (int)(id & 255), yy = (int)(id >> 8);
      ushort v = f2b(emb[(size_t)akey[yy]*E_ + e]);
      aemb[yy*E_ + e] = v;
      aembT[e*Y_ + yy] = v;
    } else if ((id -= N2) < N3){
      int a = (int)(id & 31), yy = (int)(id >> 5);
      avec[yy*32 + a] = attab[atype[yy]*32 + a];
    } else if ((id -= N3) < N4){
      int e = (int)(id & 255); long tb = id >> 8; int bb = (int)(tb & 31); int t = (int)(tb >> 5);
      acat[(size_t)tb*512 + e] = f2b(emb[(size_t)croom[bb*SOUT_ + t]*E_ + e]);
    } else { id -= N4;
      int yy = (int)(id & 255); long tb = id >> 8; int bb = (int)(tb & 31); int t = (int)(tb >> 5);
      yprev[id] = (t == 0) ? (ushort)0 : f2b(yv[((size_t)bb*SOUT_ + (t-1))*Y_ + yy]);
    }
  }
}

// all f32->bf16 weight conversions in one kernel
__global__ __launch_bounds__(256)
void k_convall(const float* __restrict__ eWihF, const float* __restrict__ eWihB,
               const float* __restrict__ transW, const float* __restrict__ dWih,
               const float* __restrict__ cW1, const float* __restrict__ dWhh,
               ushort* __restrict__ WihFb, ushort* __restrict__ WihBb,
               ushort* __restrict__ Wtrb, ushort* __restrict__ Wattb,
               ushort* __restrict__ Wcat2b, ushort* __restrict__ W1attb,
               ushort* __restrict__ Wdecb, ushort* __restrict__ Wchk2b)
{
  const long N1 = 393216;   // WihFb  (TH x 256 copy)
  const long N2 = 393216;   // WihBb
  const long N3 = 262144;   // Wtrb   (256 x 1024 copy)
  const long N4 = 1572864;  // Wattb  (TH x 1024, sld 1569)
  const long N5 = 393216;   // Wcat2b room (TH x 256, sld1569 off1025, dld512)
  const long N6 = 393216;   // Wcat2b y    (off1313, dst off256)
  const long N7 = 524288;   // W1attb (512 x 1024, sld 1568)
  const long N8 = 786432;   // Wdecb  (TH x 512 copy)
  const long N9 = 262144;   // Wchk2b (512 x 512, sld1568 off1056)
  const long NT = N1+N2+N3+N4+N5+N6+N7+N8+N9;
  for (long i = (long)blockIdx.x*256 + threadIdx.x; i < NT; i += (long)gridDim.x*256){
    long id = i;
    if (id < N1){ WihFb[id] = f2b(eWihF[id]); }
    else if ((id -= N1) < N2){ WihBb[id] = f2b(eWihB[id]); }
    else if ((id -= N2) < N3){ Wtrb[id] = f2b(transW[id]); }
    else if ((id -= N3) < N4){
      const long r = id>>10, c = id&1023;
      Wattb[id] = f2b(dWih[r*1569 + c]);
    }
    else if ((id -= N4) < N5){
      const long r = id>>8, c = id&255;
      Wcat2b[r*512 + c] = f2b(dWih[r*1569 + 1025 + c]);
    }
    else if ((id -= N5) < N6){
      const long r = id>>8, c = id&255;
      Wcat2b[r*512 + 256 + c] = f2b(dWih[r*1569 + 1313 + c]);
    }
    else if ((id -= N6) < N7){
      const long r = id>>10, c = id&1023;
      W1attb[id] = f2b(cW1[r*1568 + c]);
    }
    else if ((id -= N7) < N8){ Wdecb[id] = f2b(dWhh[id]); }
    else { id -= N8;
      const long r = id>>9, c = id&511;
      Wchk2b[id] = f2b(cW1[r*1568 + 1056 + c]);
    }
  }
}

// add_y, addc_y, wchk, dbhh_rz
__global__ void k_prep2(const float* __restrict__ avec, const float* __restrict__ decWih,
                        const float* __restrict__ dbih, const float* __restrict__ cW1,
                        const float* __restrict__ cb1, const float* __restrict__ dbhh,
                        float* __restrict__ addy, float* __restrict__ addcy,
                        float* __restrict__ wchk, float* __restrict__ dbhhrz)
{
  const long NA = (long)Y_*TH_;
  const long NB = (long)Y_*H_;
  for (long i = (long)blockIdx.x*blockDim.x + threadIdx.x; i < NA+NB+TH_+TH_; i += (long)gridDim.x*blockDim.x){
    long id = i;
    if (id < NA){
      int n = (int)(id % TH_), yy = (int)(id / TH_);
      float s = dbih[n];
      const float* wr = decWih + (size_t)n*1569 + 1281;
      const float* av = avec + yy*32;
      #pragma unroll
      for (int a=0;a<32;++a) s += av[a]*wr[a];
      addy[id] = s;
    } else if ((id -= NA) < NB){
      int n = (int)(id & 511), yy = (int)(id >> 9);
      float s = cb1[n];
      const float* wr = cW1 + (size_t)n*1568 + 1024;
      const float* av = avec + yy*32;
      #pragma unroll
      for (int a=0;a<32;++a) s += av[a]*wr[a];
      addcy[id] = s;
    } else if ((id -= NB) < TH_){
      wchk[id] = decWih[(size_t)id*1569 + 1024];
    } else { id -= TH_;
      dbhhrz[id] = (id < 1024) ? dbhh[id] : 0.f;
    }
  }
}

// ---------------- bf16 NT GEMM: C[M,N] = A[M,K] @ W[N,K]^T  (MFMA 16x16x32) ----------------
#define GF_BIAS 1
#define GF_TANH 2
#define GF_WF32 4
#define GF_WBF16 8
#define GF_ADDY 32
#define GF_CHK 64
#define GF_ESUM 128

template<int FLAGS>
__global__ __launch_bounds__(256)
void gemm_nt(const ushort* __restrict__ A, const ushort* __restrict__ W,
             const float* __restrict__ bias,
             const float* __restrict__ addy, int lday,
             float* __restrict__ Cf, ushort* __restrict__ Cb, int ldC,
             int K, int ldA, int ldW, int n0,
             long zA, long zW, long zC,
             const ushort* __restrict__ chkbase)
{
  const int z = blockIdx.z;
  A += (long)z*zA; W += (long)z*zW;
  const int bn = n0 + (blockIdx.x<<7);
  const int bm = (blockIdx.y<<7);
  const int tid = threadIdx.x;
  const int w = tid>>6, lane = tid&63;
  const int wm = (w>>1)<<6, wn = (w&1)<<6;
  const int rs = tid>>1;
  const int kh = (tid&1)<<5;
  __shared__ ushort lsA[8192];
  __shared__ ushort lsB[8192];
  f32x4 acc[4][4];
  #pragma unroll
  for (int i=0;i<4;++i)
    #pragma unroll
    for (int jj=0;jj<4;++jj) acc[i][jj] = 0.f;

  const ushort* pa = A + (size_t)(bm+rs)*ldA + kh;
  const ushort* pb = W + (size_t)(bn+rs)*ldW + kh;
  uint4 va[4], vb[4];
  #pragma unroll
  for (int i=0;i<4;++i){ va[i] = *(const uint4*)(pa + i*8); vb[i] = *(const uint4*)(pb + i*8); }
  const int nkt = K>>6;
  for (int kt=0; kt<nkt; ++kt){
    __syncthreads();
    #pragma unroll
    for (int i=0;i<4;++i){
      const int c = ((tid&1)<<2) + i;
      *(uint4*)&lsA[(size_t)((c<<7) + rs)<<3] = va[i];
      *(uint4*)&lsB[(size_t)((c<<7) + rs)<<3] = vb[i];
    }
    __syncthreads();
    if (kt+1 < nkt){
      const ushort* qa = pa + (size_t)(kt+1)*64;
      const ushort* qb = pb + (size_t)(kt+1)*64;
      #pragma unroll
      for (int i=0;i<4;++i){ va[i] = *(const uint4*)(qa + i*8); vb[i] = *(const uint4*)(qb + i*8); }
    }
    #pragma unroll
    for (int ks=0;ks<2;++ks){
      const int ch = (ks<<2) + (lane>>4);
      short8 af[4], bf[4];
      #pragma unroll
      for (int mi=0;mi<4;++mi) af[mi] = *(const short8*)&lsA[(size_t)((ch<<7) + wm + (mi<<4) + (lane&15))<<3];
      #pragma unroll
      for (int ni=0;ni<4;++ni) bf[ni] = *(const short8*)&lsB[(size_t)((ch<<7) + wn + (ni<<4) + (lane&15))<<3];
      #pragma unroll
      for (int mi=0;mi<4;++mi)
        #pragma unroll
        for (int ni=0;ni<4;++ni)
          acc[mi][ni] = __builtin_amdgcn_mfma_f32_16x16x32_bf16(af[mi], bf[ni], acc[mi][ni], 0,0,0);
    }
  }
  if (FLAGS & GF_CHK){
    // chk MLP: u = acc + chkbase ; accumulate tanh(u)*cW2[col] into chkdot[row] (Cf)
    float rsum[4][4];
    #pragma unroll
    for (int mi=0;mi<4;++mi)
      #pragma unroll
      for (int q=0;q<4;++q) rsum[mi][q] = 0.f;
    #pragma unroll
    for (int mi=0;mi<4;++mi){
      #pragma unroll
      for (int ni=0;ni<4;++ni){
        const int col = bn + wn + (ni<<4) + (lane&15);
        const float w2v = addy[col];
        const int row0 = bm + wm + (mi<<4) + ((lane>>4)<<2);
        #pragma unroll
        for (int q=0;q<4;++q){
          const float u = acc[mi][ni][q] + b2f(chkbase[(size_t)(row0+q)*H_ + col]);
          rsum[mi][q] += tanh_fast(u) * w2v;
        }
      }
    }
    #pragma unroll
    for (int mi=0;mi<4;++mi)
      #pragma unroll
      for (int q=0;q<4;++q){
        float v = rsum[mi][q];
        v += __shfl_xor(v,1); v += __shfl_xor(v,2); v += __shfl_xor(v,4); v += __shfl_xor(v,8);
        if ((lane&15)==0){
          const int row = bm + wm + (mi<<4) + ((lane>>4)<<2) + q;
          atomicAdd(&Cf[row], v);
        }
      }
  } else {
    const long zc = (long)z*zC;
    #pragma unroll
    for (int mi=0;mi<4;++mi){
      #pragma unroll
      for (int ni=0;ni<4;++ni){
        const int col = bn + wn + (ni<<4) + (lane&15);
        const int row0 = bm + wm + (mi<<4) + ((lane>>4)<<2);
        float bv = 0.f;
        if (FLAGS & GF_BIAS) bv = bias[col];
        #pragma unroll
        for (int q=0;q<4;++q){
          const int row = row0 + q;
          float xv = acc[mi][ni][q] + bv;
          if (FLAGS & GF_ADDY) xv += addy[(size_t)(row&255)*lday + col];
          if (FLAGS & GF_TANH) xv = tanh_fast(xv);
          if (FLAGS & GF_ESUM) xv += b2f(chkbase[((size_t)(row&127)*32 + (row>>7))*256 + col]);
          if (FLAGS & GF_WF32)  Cf[zc + (size_t)row*ldC + col] = xv;
          if (FLAGS & GF_WBF16) Cb[zc + (size_t)row*ldC + col] = f2b(xv);
        }
      }
    }
  }
}

// ---------------- persistent bi-GRU encoder (fence-free sc1 exchange) ----------------
__global__ __launch_bounds__(256,1)
void enc_persist(const float* __restrict__ Wf, const float* __restrict__ Wb,
                 const float* __restrict__ bhf, const float* __restrict__ bhb,
                 const ushort* __restrict__ gif, const ushort* __restrict__ gib,
                 ushort* __restrict__ hG, uint* __restrict__ flags,
                 ushort* __restrict__ encout, ushort* __restrict__ encoutT,
                 float* __restrict__ hTf, float* __restrict__ hTb)
{
  const int g = blockIdx.x;
  const int dir = g >> 5;
  const int j0 = (g & 31) << 4;
  const int tid = threadIdx.x;
  const int w = tid >> 6, lane = tid & 63;
  const int mi = w & 1, kh = w >> 1;
  const int l15 = lane & 15, l4 = lane >> 4;
  const int brow0 = mi*16 + l4*4;

  const float* W = dir ? Wb : Wf;
  const float* bh = dir ? bhb : bhf;
  const ushort* gi = dir ? gib : gif;

  __shared__ __align__(16) float cred[2][3][256];
  __shared__ float bhl[48];

  short8 bw[3][8];
  {
    const int kbase = kh*256 + l4*8;
    #pragma unroll
    for (int ni=0; ni<3; ++ni){
      const float* wr = W + (size_t)(ni*512 + j0 + l15)*512 + kbase;
      #pragma unroll
      for (int ks=0; ks<8; ++ks){
        const float4 f0 = *(const float4*)(wr + ks*32);
        const float4 f1 = *(const float4*)(wr + ks*32 + 4);
        short8 v;
        v[0]=(short)f2b(f0.x); v[1]=(short)f2b(f0.y); v[2]=(short)f2b(f0.z); v[3]=(short)f2b(f0.w);
        v[4]=(short)f2b(f1.x); v[5]=(short)f2b(f1.y); v[6]=(short)f2b(f1.z); v[7]=(short)f2b(f1.w);
        bw[ni][ks] = v;
      }
    }
  }
  if (tid < 48) bhl[tid] = bh[(tid>>4)*512 + j0 + (tid&15)];
  __syncthreads();

  float bh0r=0.f, bh1r=0.f, bh2r=0.f;
  if (kh==0){ bh0r = bhl[l15]; bh1r = bhl[16+l15]; bh2r = bhl[32+l15]; }
  float holdr[4] = {0.f,0.f,0.f,0.f};
  uint* myflag = flags + dir*32 + (g&31);

  for (int t=0; t<128; ++t){
    const int tt = dir ? (127 - t) : t;
    // gi prefetch (independent of the flag wait; issued by kh==0 waves only)
    float giv0[4], giv1[4], giv2[4];
    if (kh==0){
      const ushort* girow = gi + ((size_t)tt*32 + brow0)*1536 + j0 + l15;
      #pragma unroll
      for (int q=0; q<4; ++q){
        giv0[q] = b2f(girow[q*1536]);
        giv1[q] = b2f(girow[q*1536 + 512]);
        giv2[q] = b2f(girow[q*1536 + 1024]);
      }
    }
    if (t){
      // poll on wave 2 (kh==1): its vmcnt(0) polls don't stall the gi prefetch
      if ((tid>>6)==2 && (tid&63)<32){
        const uint* fp = flags + dir*32 + (tid&31);
        while (ld_flag(fp) < (uint)t) __builtin_amdgcn_s_sleep(2);
      }
      __syncthreads();
    }
    const ushort* hsrc = hG + ((size_t)((t&1)*2 + dir))*32768 + (size_t)(mi*16+l15)*1024 + kh*256 + l4*8;
    u32x4 a0,a1,a2,a3,a4,a5,a6,a7,b0,b1,b2,b3,b4,b5,b6,b7;
    asm volatile(
      "global_load_dwordx4 %0, %16, off sc0 sc1\n\t"
      "global_load_dwordx4 %1, %16, off offset:64 sc0 sc1\n\t"
      "global_load_dwordx4 %2, %16, off offset:128 sc0 sc1\n\t"
      "global_load_dwordx4 %3, %16, off offset:192 sc0 sc1\n\t"
      "global_load_dwordx4 %4, %16, off offset:256 sc0 sc1\n\t"
      "global_load_dwordx4 %5, %16, off offset:320 sc0 sc1\n\t"
      "global_load_dwordx4 %6, %16, off offset:384 sc0 sc1\n\t"
      "global_load_dwordx4 %7, %16, off offset:448 sc0 sc1\n\t"
      "global_load_dwordx4 %8, %16, off offset:1024 sc0 sc1\n\t"
      "global_load_dwordx4 %9, %16, off offset:1088 sc0 sc1\n\t"
      "global_load_dwordx4 %10, %16, off offset:1152 sc0 sc1\n\t"
      "global_load_dwordx4 %11, %16, off offset:1216 sc0 sc1\n\t"
      "global_load_dwordx4 %12, %16, off offset:1280 sc0 sc1\n\t"
      "global_load_dwordx4 %13, %16, off offset:1344 sc0 sc1\n\t"
      "global_load_dwordx4 %14, %16, off offset:1408 sc0 sc1\n\t"
      "global_load_dwordx4 %15, %16, off offset:1472 sc0 sc1\n\t"
      "s_waitcnt vmcnt(0)"
      : "=&v"(a0),"=&v"(a1),"=&v"(a2),"=&v"(a3),"=&v"(a4),"=&v"(a5),"=&v"(a6),"=&v"(a7),
        "=&v"(b0),"=&v"(b1),"=&v"(b2),"=&v"(b3),"=&v"(b4),"=&v"(b5),"=&v"(b6),"=&v"(b7)
      : "v"(hsrc)
      : "memory");
    const short8 ah[8] = {cvt8(a0),cvt8(a1),cvt8(a2),cvt8(a3),cvt8(a4),cvt8(a5),cvt8(a6),cvt8(a7)};
    const short8 al[8] = {cvt8(b0),cvt8(b1),cvt8(b2),cvt8(b3),cvt8(b4),cvt8(b5),cvt8(b6),cvt8(b7)};
    f32x4 acc[3]; acc[0]=0.f; acc[1]=0.f; acc[2]=0.f;
    #pragma unroll
    for (int ks=0; ks<8; ++ks){
      acc[0] = __builtin_amdgcn_mfma_f32_16x16x32_bf16(ah[ks], bw[0][ks], acc[0],0,0,0);
      acc[1] = __builtin_amdgcn_mfma_f32_16x16x32_bf16(ah[ks], bw[1][ks], acc[1],0,0,0);
      acc[2] = __builtin_amdgcn_mfma_f32_16x16x32_bf16(ah[ks], bw[2][ks], acc[2],0,0,0);
      acc[0] = __builtin_amdgcn_mfma_f32_16x16x32_bf16(al[ks], bw[0][ks], acc[0],0,0,0);
      acc[1] = __builtin_amdgcn_mfma_f32_16x16x32_bf16(al[ks], bw[1][ks], acc[1],0,0,0);
      acc[2] = __builtin_amdgcn_mfma_f32_16x16x32_bf16(al[ks], bw[2][ks], acc[2],0,0,0);
    }
    if (kh==1){
      #pragma unroll
      for (int ni=0; ni<3; ++ni) *(f32x4*)&cred[mi][ni][lane*4] = acc[ni];
    }
    __syncthreads();
    if (kh==0){
      #pragma unroll
      for (int ni=0; ni<3; ++ni){
        const f32x4 o = *(const f32x4*)&cred[mi][ni][lane*4];
        acc[ni][0]+=o[0]; acc[ni][1]+=o[1]; acc[ni][2]+=o[2]; acc[ni][3]+=o[3];
      }
      ushort* dst = hG + ((size_t)(((t+1)&1)*2 + dir))*32768;
      #pragma unroll
      for (int q=0; q<4; ++q){
        const int b = brow0 + q;
        const float r  = sigf(giv0[q] + acc[0][q] + bh0r);
        const float zg = sigf(giv1[q] + acc[1][q] + bh1r);
        const float n  = tanh_fast(giv2[q] + r*(acc[2][q] + bh2r));
        const float h2 = (1.f - zg)*n + zg*holdr[q];
        holdr[q] = h2;
        const ushort hb = f2b(h2);
        const ushort hl = f2b(h2 - b2f(hb));
        if (t < 127){
          st_h16(dst + (size_t)b*1024 + j0 + l15, (uint)hb);
          st_h16(dst + (size_t)b*1024 + 512 + j0 + l15, (uint)hl);
        }
        encout[((size_t)b*SIN_ + tt)*1024 + dir*H_ + j0 + l15] = hb;
        encoutT[((size_t)b*1024 + dir*H_ + j0 + l15)*SIN_ + tt] = hb;
      }
    }
    __syncthreads();   // drains all waves' stores before flag
    if (t < 127 && tid == 0) st_flag(myflag, (uint)(t+1));
  }
  if (kh==0){
    float* hT = dir ? hTb : hTf;
    #pragma unroll
    for (int q=0; q<4; ++q) hT[(size_t)(brow0+q)*H_ + j0 + l15] = holdr[q];
  }
}

// row softmax over SIN=128, one wave per row
__global__ __launch_bounds__(256) void k_softmax(const float* __restrict__ sc, ushort* __restrict__ al)
{
  const int row = blockIdx.x*4 + (threadIdx.x>>6);
  const int lane = threadIdx.x&63;
  const float* s = sc + (size_t)row*SIN_;
  const float2 v = *(const float2*)&s[lane*2];
  float m = fmaxf(v.x, v.y);
  #pragma unroll
  for (int o=1;o<64;o<<=1) m = fmaxf(m, __shfl_xor(m, o));
  const float e0 = __expf(v.x - m), e1 = __expf(v.y - m);
  float sum = e0 + e1;
  #pragma unroll
  for (int o=1;o<64;o<<=1) sum += __shfl_xor(sum, o);
  const float inv = 1.f/sum;
  ushort* a = al + (size_t)row*SIN_;
  const uint pkv = (uint)f2b(e0*inv) | ((uint)f2b(e1*inv)<<16);
  *(uint*)&a[lane*2] = pkv;
}

// h0_dec = tanh(hidden_cat @ merge_W^T + merge_b)
__global__ __launch_bounds__(512)
void k_merge(const float* __restrict__ hTf, const float* __restrict__ hTb,
             const float* __restrict__ mW, const float* __restrict__ mb,
             float* __restrict__ h0)
{
  const int b = blockIdx.x, j = threadIdx.x;
  __shared__ float hc[1024];
  for (int i=j; i<1024; i+=512){
    const int half = i >> 9, jj = i & 511;
    hc[i] = (b < 16) ? hTf[(size_t)(2*b + half)*H_ + jj] : hTb[(size_t)(2*(b-16) + half)*H_ + jj];
  }
  __syncthreads();
  float d = mb[j];
  const float* wr = mW + (size_t)j*1024;
  #pragma unroll 8
  for (int k=0;k<1024;k+=4){
    const float4 a = *(const float4*)&wr[k];
    const float4 hh = *(const float4*)&hc[k];
    d += a.x*hh.x + a.y*hh.y + a.z*hh.z + a.w*hh.w;
  }
  h0[(size_t)b*H_ + j] = tanh_fast(d);
}

__global__ void k_bcast(const float* __restrict__ h0, ushort* __restrict__ hb,
                        float* __restrict__ chkdot, float* __restrict__ logits)
{
  for (long i = (long)blockIdx.x*blockDim.x + threadIdx.x; i < (long)8192*H_; i += (long)gridDim.x*blockDim.x){
    const int jj = (int)(i & 511); const long row = i >> 9; const int bb = (int)(row >> 8);
    hb[i] = f2b(h0[(size_t)bb*H_ + jj]);
    if (i < 8192){ chkdot[i] = 0.f; logits[i] = 0.f; }
  }
}

// ---------------- fused decoder recurrent GEMM + gates + logit partials ----------------
// grid (4, 64): bx = 128-j block, by = 128-row block. 512 threads = 8 waves (2 row x 4 col).
__global__ __launch_bounds__(512,1)
void gemm_dec(const ushort* __restrict__ A, const ushort* __restrict__ Wd,
              const ushort* __restrict__ gib, const float* __restrict__ sproj_t,
              const float* __restrict__ wchk, const float* __restrict__ dbhh,
              const float* __restrict__ checked, int t,
              const float* __restrict__ decW,
              ushort* __restrict__ h2bo, float* __restrict__ logits)
{
  const int bx = blockIdx.x;
  const int by = blockIdx.y;
  const int bm = by<<7;
  const int tid = threadIdx.x;
  const int w = tid>>6, lane = tid&63;
  const int wrh = w>>2, wc = w&3;
  const int wm = wrh<<6;
  const int l15 = lane&15, l4 = lane>>4;
  __shared__ ushort lsA[128*72];
  __shared__ ushort lsB[384*72];
  f32x4 acc[3][4][2];
  #pragma unroll
  for (int gg=0;gg<3;++gg)
    #pragma unroll
    for (int mi2=0;mi2<4;++mi2)
      #pragma unroll
      for (int ni2=0;ni2<2;++ni2) acc[gg][mi2][ni2] = 0.f;

  const int saRow0 = tid>>3, saK = (tid&7)<<3;
  uint4 va[2], vb[6];
  {
    #pragma unroll
    for (int i=0;i<2;++i){
      const int row = saRow0 + (i<<6);
      va[i] = *(const uint4*)&A[(size_t)(bm+row)*512 + saK];
    }
    #pragma unroll
    for (int i=0;i<6;++i){
      const int s = tid + (i<<9);
      const int gg = s>>10, w1 = s&1023, row = w1>>3, kc = (w1&7)<<3;
      vb[i] = *(const uint4*)&Wd[(size_t)((gg<<9) + (bx<<7) + row)*512 + kc];
    }
  }
  for (int kt=0; kt<8; ++kt){
    __syncthreads();
    #pragma unroll
    for (int i=0;i<2;++i){
      const int row = saRow0 + (i<<6);
      *(uint4*)&lsA[row*72 + saK] = va[i];
    }
    #pragma unroll
    for (int i=0;i<6;++i){
      const int s = tid + (i<<9);
      const int gg = s>>10, w1 = s&1023, row = w1>>3, kc = (w1&7)<<3;
      *(uint4*)&lsB[((gg<<7)+row)*72 + kc] = vb[i];
    }
    __syncthreads();
    if (kt < 7){
      const int ko = (kt+1)<<6;
      #pragma unroll
      for (int i=0;i<2;++i){
        const int row = saRow0 + (i<<6);
        va[i] = *(const uint4*)&A[(size_t)(bm+row)*512 + ko + saK];
      }
      #pragma unroll
      for (int i=0;i<6;++i){
        const int s = tid + (i<<9);
        const int gg = s>>10, w1 = s&1023, row = w1>>3, kc = (w1&7)<<3;
        vb[i] = *(const uint4*)&Wd[(size_t)((gg<<9) + (bx<<7) + row)*512 + ko + kc];
      }
    }
    #pragma unroll
    for (int ks=0;ks<2;++ks){
      short8 af[4];
      #pragma unroll
      for (int mi2=0;mi2<4;++mi2)
        af[mi2] = *(const short8*)&lsA[(wm + (mi2<<4) + l15)*72 + (ks<<5) + (l4<<3)];
      short8 bf[3][2];
      #pragma unroll
      for (int gg=0;gg<3;++gg)
        #pragma unroll
        for (int ni2=0;ni2<2;++ni2)
          bf[gg][ni2] = *(const short8*)&lsB[((gg<<7) + (wc<<5) + (ni2<<4) + l15)*72 + (ks<<5) + (l4<<3)];
      #pragma unroll
      for (int gg=0;gg<3;++gg)
        #pragma unroll
        for (int mi2=0;mi2<4;++mi2)
          #pragma unroll
          for (int ni2=0;ni2<2;++ni2)
            acc[gg][mi2][ni2] = __builtin_amdgcn_mfma_f32_16x16x32_bf16(af[mi2], bf[gg][ni2], acc[gg][mi2][ni2], 0,0,0);
    }
  }
  // epilogue: gates + logit partials
  const int bb = by>>1;
  const float* sp = sproj_t + (size_t)bb*TH_;
  const int jbase = (bx<<7) + (wc<<5);
  float spv[3][2], wcv[3][2], bhnv[2], dwv[2];
  #pragma unroll
  for (int ni2=0;ni2<2;++ni2){
    const int j = jbase + (ni2<<4) + l15;
    spv[0][ni2] = sp[j]; spv[1][ni2] = sp[512+j]; spv[2][ni2] = sp[1024+j];
    wcv[0][ni2] = wchk[j]; wcv[1][ni2] = wchk[512+j]; wcv[2][ni2] = wchk[1024+j];
    bhnv[ni2] = dbhh[1024+j];
    dwv[ni2] = decW[j];
  }
  const float* ckrow = checked + ((size_t)(bb*33 + t))*Y_;
  float lrow[4][4];
  #pragma unroll
  for (int mi2=0;mi2<4;++mi2)
    #pragma unroll
    for (int q=0;q<4;++q) lrow[mi2][q] = 0.f;
  #pragma unroll
  for (int mi2=0;mi2<4;++mi2){
    #pragma unroll
    for (int q=0;q<4;++q){
      const int row = bm + wm + (mi2<<4) + (l4<<2) + q;
      const float ck = ckrow[row & 255];
      #pragma unroll
      for (int ni2=0;ni2<2;++ni2){
        const int j = jbase + (ni2<<4) + l15;
        const float g0 = b2f(gib[(size_t)row*TH_ + j]);
        const float g1 = b2f(gib[(size_t)row*TH_ + 512 + j]);
        const float g2 = b2f(gib[(size_t)row*TH_ + 1024 + j]);
        const float hold = b2f(A[(size_t)row*H_ + j]);
        const float r  = sigf(g0 + spv[0][ni2] + ck*wcv[0][ni2] + acc[0][mi2][ni2][q]);
        const float zg = sigf(g1 + spv[1][ni2] + ck*wcv[1][ni2] + acc[1][mi2][ni2][q]);
        const float n  = tanh_fast(g2 + spv[2][ni2] + ck*wcv[2][ni2] + r*(acc[2][mi2][ni2][q] + bhnv[ni2]));
        const float h2 = (1.f - zg)*n + zg*hold;
        h2bo[(size_t)row*H_ + j] = f2b(h2);
        lrow[mi2][q] += h2 * dwv[ni2];
      }
    }
  }
  #pragma unroll
  for (int mi2=0;mi2<4;++mi2)
    #pragma unroll
    for (int q=0;q<4;++q){
      float v = lrow[mi2][q];
      v += __shfl_xor(v,1); v += __shfl_xor(v,2); v += __shfl_xor(v,4); v += __shfl_xor(v,8);
      if (l15==0){
        const int row = bm + wm + (mi2<<4) + (l4<<2) + q;
        atomicAdd(&logits[row], v);
      }
    }
}

// ---------------- per-step losses (small) ----------------
__global__ __launch_bounds__(256)
void dec_loss(float* __restrict__ chkdot, const float* __restrict__ cb2v,
              const float* __restrict__ checked, const float* __restrict__ yv,
              float* __restrict__ logits, int t, float* __restrict__ acc)
{
  const int tid = threadIdx.x;
  if (blockIdx.x < 32){
    const int row = blockIdx.x*256 + tid;
    const int bb = row>>8, yy = row&255;
    const float u = chkdot[row] + cb2v[0];
    chkdot[row] = 0.f;
    const float c = checked[((size_t)bb*33 + (t+1))*Y_ + yy];
    const float yt = yv[((size_t)bb*SOUT_ + t)*Y_ + yy];
    float wv = yt * (c*splus(-u) + (1.f-c)*splus(u));
    __shared__ float red[256];
    red[tid] = wv; __syncthreads();
    for (int o=128;o;o>>=1){ if (tid<o) red[tid] += red[tid+o]; __syncthreads(); }
    if (tid==0) atomicAdd(acc+1, red[0]);
  } else {
    __shared__ float red[256];
    __shared__ float bmx[32], bsm[32];
    const int bb = tid>>3, part = tid&7;
    float lv[32];
    const float* lg = logits + bb*Y_ + part*32;
    float m = -1e30f;
    #pragma unroll
    for (int i=0;i<32;++i){ lv[i] = lg[i]; m = fmaxf(m, lv[i]); }
    red[tid] = m; __syncthreads();
    if (part==0){ float mm = red[tid];
      #pragma unroll
      for (int k2=1;k2<8;++k2) mm = fmaxf(mm, red[tid+k2]);
      bmx[bb] = mm; }
    __syncthreads();
    const float bm = bmx[bb];
    float se = 0.f;
    #pragma unroll
    for (int i=0;i<32;++i) se += __expf(lv[i]-bm);
    red[tid] = se; __syncthreads();
    if (part==0){ float ss = 0.f;
      #pragma unroll
      for (int k2=0;k2<8;++k2) ss += red[tid+k2];
      bsm[bb] = ss; }
    __syncthreads();
    const float lse = bm + logf(bsm[bb]);
    const float* yr = yv + ((size_t)bb*SOUT_ + t)*Y_ + part*32;
    float pl = 0.f;
    #pragma unroll
    for (int i=0;i<32;++i) pl += yr[i]*(lv[i]-lse);
    red[tid] = pl; __syncthreads();
    if (tid==0){ float s = 0.f;
      for (int k2=0;k2<256;++k2) s += red[k2];
      atomicAdd(acc+0, -s); }
    __syncthreads();
    for (int i=tid; i<8192; i+=256) logits[i] = 0.f;
  }
}

__global__ void k_final(const float* __restrict__ acc, float* __restrict__ out)
{
  if (threadIdx.x==0){
    const float ls = acc[0], cls = acc[1], ys = acc[2];
    out[0] = (ls+cls)/ys; out[1] = ls/ys; out[2] = cls/ys;
  }
}

// ---------------- host ----------------
extern "C" void kernel_launch(void* const* d_in, const int* in_sizes, int n_in,
                              void* d_out, int out_size, void* d_ws, size_t ws_size,
                              hipStream_t stream)
{
  (void)in_sizes; (void)n_in; (void)out_size;
  const int*   x      = (const int*)d_in[0];
  const int*   akey   = (const int*)d_in[1];
  const int*   atype  = (const int*)d_in[2];
  const int*   croom  = (const int*)d_in[3];
  const float* checked= (const float*)d_in[4];
  const float* yv     = (const float*)d_in[5];
  const float* emb    = (const float*)d_in[6];
  const float* attab  = (const float*)d_in[7];
  const float* eWihF  = (const float*)d_in[8];
  const float* eWhhF  = (const float*)d_in[9];
  const float* ebihF  = (const float*)d_in[10];
  const float* ebhhF  = (const float*)d_in[11];
  const float* eWihB  = (const float*)d_in[12];
  const float* eWhhB  = (const float*)d_in[13];
  const float* ebihB  = (const float*)d_in[14];
  const float* ebhhB  = (const float*)d_in[15];
  const float* transW = (const float*)d_in[16];
  const float* transb = (const float*)d_in[17];
  const float* mergeW = (const float*)d_in[18];
  const float* mergeb = (const float*)d_in[19];
  const float* dWih   = (const float*)d_in[20];
  const float* dWhh   = (const float*)d_in[21];
  const float* dbih   = (const float*)d_in[22];
  const float* dbhh   = (const float*)d_in[23];
  const float* dW     = (const float*)d_in[24];
  const float* cW1    = (const float*)d_in[26];
  const float* cb1    = (const float*)d_in[27];
  const float* cW2    = (const float*)d_in[28];
  const float* cb2    = (const float*)d_in[29];

  char* base = (char*)d_ws;
  size_t off = 0;
  auto alloc = [&](size_t bytes)->char*{ char* p = base + off; off += (bytes + 255) & ~(size_t)255; return p; };

  float*  accv   = (float*)alloc(256);
  ushort* embxs  = (ushort*)alloc((size_t)SIN_*B_*E_*2);
  ushort* aemb   = (ushort*)alloc((size_t)Y_*E_*2);
  ushort* aembT  = (ushort*)alloc((size_t)Y_*E_*2);
  float*  avec   = (float*)alloc((size_t)Y_*32*4);
  ushort* yprev  = (ushort*)alloc((size_t)SOUT_*B_*Y_*2);
  ushort* acat   = (ushort*)alloc((size_t)SOUT_*B_*512*2);
  ushort* gi_fb  = (ushort*)alloc((size_t)2*SIN_*B_*TH_*2);   // gi_f | gi_b ; later aliased by gi_base
  ushort* gi_f   = gi_fb;
  ushort* gi_b   = gi_fb + (size_t)SIN_*B_*TH_;
  ushort* gibase = gi_fb;
  ushort* encout = (ushort*)alloc((size_t)B_*SIN_*1024*2);
  ushort* encoutT= (ushort*)alloc((size_t)B_*1024*SIN_*2);
  float*  hTf    = (float*)alloc((size_t)B_*H_*4);
  float*  hTb    = (float*)alloc((size_t)B_*H_*4);
  float*  h0dec  = (float*)alloc((size_t)B_*H_*4);
  ushort* esum   = (ushort*)alloc((size_t)B_*SIN_*E_*2);
  float*  scores = (float*)alloc((size_t)B_*Y_*SIN_*4);
  ushort* alpha  = (ushort*)alloc((size_t)B_*Y_*SIN_*2);
  ushort* att    = (ushort*)alloc((size_t)8192*1024*2);
  ushort* chkbase= (ushort*)alloc((size_t)8192*H_*2);
  float*  addy   = (float*)alloc((size_t)Y_*TH_*4);
  float*  addcy  = (float*)alloc((size_t)Y_*H_*4);
  float*  sproj  = (float*)alloc((size_t)SOUT_*B_*TH_*4);
  float*  wchk   = (float*)alloc((size_t)TH_*4);
  float*  dbhhrz = (float*)alloc((size_t)TH_*4);
  ushort* WihFb  = (ushort*)alloc((size_t)TH_*E_*2);
  ushort* WihBb  = (ushort*)alloc((size_t)TH_*E_*2);
  ushort* Wtrb   = (ushort*)alloc((size_t)E_*1024*2);
  ushort* Wattb  = (ushort*)alloc((size_t)TH_*1024*2);
  ushort* Wcat2b = (ushort*)alloc((size_t)TH_*512*2);
  ushort* W1attb = (ushort*)alloc((size_t)H_*1024*2);
  ushort* Wdecb  = (ushort*)alloc((size_t)TH_*512*2);
  ushort* Wchk2b = (ushort*)alloc((size_t)512*512*2);
  ushort* h2bA   = (ushort*)alloc((size_t)8192*H_*2);
  ushort* h2bB   = (ushort*)alloc((size_t)8192*H_*2);
  float*  chkdot = (float*)alloc((size_t)8192*4);
  float*  logits = (float*)alloc((size_t)8192*4);
  ushort* hG     = (ushort*)alloc((size_t)2*2*32*1024*2);
  uint*   flags  = (uint*)alloc((size_t)256*4);

  if (off > ws_size){ k_wsfail<<<1,1,0,stream>>>((float*)d_out); return; }

  float* outp = (float*)d_out;

  k_init<<<dim3(1), dim3(64), 0, stream>>>(accv);
  k_init_enc<<<dim3(64), dim3(256), 0, stream>>>(flags, hG);
  k_ysum<<<dim3(256), dim3(256), 0, stream>>>(yv, accv);
  k_lookup<<<dim3(2048), dim3(256), 0, stream>>>(x, akey, atype, croom, yv, emb, attab,
                                                 embxs, aemb, aembT, avec, acat, yprev);
  k_convall<<<dim3(2048), dim3(256), 0, stream>>>(eWihF, eWihB, transW, dWih, cW1, dWhh,
                                                  WihFb, WihBb, Wtrb, Wattb, Wcat2b, W1attb, Wdecb, Wchk2b);
  k_prep2<<<dim3(1024), dim3(256), 0, stream>>>(avec, dWih, dbih, cW1, cb1, dbhh,
                                                addy, addcy, wchk, dbhhrz);

  // encoder input projections (bias folded in)
  gemm_nt<(GF_BIAS|GF_WBF16)><<<dim3(12,32,1), dim3(256), 0, stream>>>(
    embxs, WihFb, ebihF, nullptr, 0, nullptr, gi_f, TH_, E_, E_, E_, 0, 0L,0L,0L, nullptr);
  gemm_nt<(GF_BIAS|GF_WBF16)><<<dim3(12,32,1), dim3(256), 0, stream>>>(
    embxs, WihBb, ebihB, nullptr, 0, nullptr, gi_b, TH_, E_, E_, E_, 0, 0L,0L,0L, nullptr);

  enc_persist<<<dim3(64), dim3(256), 0, stream>>>(eWhhF, eWhhB, ebhhF, ebhhB, gi_f, gi_b,
                                                  hG, flags, encout, encoutT, hTf, hTb);

  // esum = bf16( tanh(enc_out @ trans_W^T + b) + emb )   (fused trans+embsum)
  gemm_nt<(GF_BIAS|GF_TANH|GF_ESUM|GF_WBF16)><<<dim3(2,32,1), dim3(256), 0, stream>>>(
    encout, Wtrb, transb, nullptr, 0, nullptr, esum, E_, 1024, 1024, 1024, 0, 0L,0L,0L, embxs);

  // scores[b] = action_emb @ embsum_b^T  (batched over b)
  gemm_nt<GF_WF32><<<dim3(1,2,32), dim3(256), 0, stream>>>(
    aemb, esum, nullptr, nullptr, 0, scores, nullptr, SIN_, E_, E_, E_, 0,
    0L, (long)SIN_*E_, (long)Y_*SIN_, nullptr);
  k_softmax<<<dim3(2048), dim3(256), 0, stream>>>(scores, alpha);

  // attention[b] = alpha_b @ enc_out_b
  gemm_nt<GF_WBF16><<<dim3(8,2,32), dim3(256), 0, stream>>>(
    alpha, encoutT, nullptr, nullptr, 0, nullptr, att, 1024, SIN_, SIN_, SIN_, 0,
    (long)Y_*SIN_, (long)1024*SIN_, (long)Y_*1024, nullptr);

  k_merge<<<dim3(32), dim3(512), 0, stream>>>(hTf, hTb, mergeW, mergeb, h0dec);

  // yemb -> acat[:,256:512]
  gemm_nt<GF_WBF16><<<dim3(2,8,1), dim3(256), 0, stream>>>(
    yprev, aembT, nullptr, nullptr, 0, nullptr, acat+256, 512, Y_, Y_, Y_, 0, 0L,0L,0L, nullptr);
  // sproj = acat @ Wcat2^T + dbhh_rz
  gemm_nt<(GF_BIAS|GF_WF32)><<<dim3(12,8,1), dim3(256), 0, stream>>>(
    acat, Wcat2b, dbhhrz, nullptr, 0, sproj, nullptr, TH_, 512, 512, 512, 0, 0L,0L,0L, nullptr);

  // gi_base = att @ W_att^T + add_y[y]   ;  chk_base = att @ W1_att^T + addc_y[y]
  gemm_nt<(GF_WBF16|GF_ADDY)><<<dim3(12,64,1), dim3(256), 0, stream>>>(
    att, Wattb, nullptr, addy, TH_, nullptr, gibase, TH_, 1024, 1024, 1024, 0, 0L,0L,0L, nullptr);
  gemm_nt<(GF_WBF16|GF_ADDY)><<<dim3(4,64,1), dim3(256), 0, stream>>>(
    att, W1attb, nullptr, addcy, H_, nullptr, chkbase, H_, 1024, 1024, 1024, 0, 0L,0L,0L, nullptr);

  k_bcast<<<dim3(4096), dim3(256), 0, stream>>>(h0dec, h2bA, chkdot, logits);

  for (int t=0; t<SOUT_; ++t){
    ushort* hin_b  = (t&1) ? h2bB : h2bA;
    ushort* hout_b = (t&1) ? h2bA : h2bB;
    gemm_dec<<<dim3(4,64), dim3(512), 0, stream>>>(
      hin_b, Wdecb, gibase, sproj + (size_t)t*B_*TH_, wchk, dbhh, checked, t,
      dW, hout_b, logits);
    gemm_nt<GF_CHK><<<dim3(4,64), dim3(256), 0, stream>>>(
      hout_b, Wchk2b, nullptr, cW2, 0, chkdot, nullptr, 0, 512, 512, 512, 0,
      0L,0L,0L, chkbase);
    dec_loss<<<dim3(33), dim3(256), 0, stream>>>(chkdot, cb2, checked, yv, logits, t, accv);
  }
  k_final<<<dim3(1), dim3(1), 0, stream>>>(accv, outp);
}